// Round 1
// baseline (694.927 us; speedup 1.0000x reference)
//
#include <hip/hip_runtime.h>
#include <cstdint>
#include <cstddef>

typedef __bf16 bf16_t;
typedef __bf16 bf16x8 __attribute__((ext_vector_type(8)));
typedef float  f32x4  __attribute__((ext_vector_type(4)));

#define SEQ 2048
#define NH  16
#define HD  128
#define MM  4096   // b*s rows
#define KK  2048
#define NN  2048

// ---------------------------------------------------------------- cast fp32->bf16
__global__ __launch_bounds__(256) void cast_f32_bf16(const float* __restrict__ src,
                                                     bf16_t* __restrict__ dst, int n4) {
    int i = blockIdx.x * 256 + threadIdx.x;
    if (i >= n4) return;
    float4 v = ((const float4*)src)[i];
    union { bf16_t h[4]; uint2 u; } t;
    t.h[0] = (bf16_t)v.x; t.h[1] = (bf16_t)v.y;
    t.h[2] = (bf16_t)v.z; t.h[3] = (bf16_t)v.w;
    ((uint2*)dst)[i] = t.u;
}

// ---------------------------------------------------------------- GEMM  C = A * B^T
// A: [MM,KK] bf16 row-major; B: [NN,KK] bf16 row-major (weights are [out,in]).
// MODE 0: bf16 out scattered to Q/K layout [b,h,s,d]
// MODE 2: bf16 out to V^T layout [b,h,d,s]
// MODE 1: fp32 out row-major [MM,NN]
template<int MODE>
__global__ __launch_bounds__(256) void gemm_bt(const bf16_t* __restrict__ A,
                                               const bf16_t* __restrict__ B,
                                               void* __restrict__ Cout) {
    // fragment-native LDS: frag f (16 rows x 32 k) stored as 64 slots of 16B,
    // slot l <-> (row = f*16 + (l&15), k-chunk = (l>>4)*8) — lane-contiguous.
    __shared__ bf16_t ldsA[8 * 512];
    __shared__ bf16_t ldsB[8 * 512];

    const int tid = threadIdx.x;
    const int w = tid >> 6, l = tid & 63;
    const int lane16 = l & 15, quad = l >> 4;
    const int tm = blockIdx.y, tn = blockIdx.x;
    const int wm = w >> 1, wn = w & 1;

    const bf16_t* pA0 = A + (size_t)(tm * 128 + (2 * w + 0) * 16 + lane16) * KK + quad * 8;
    const bf16_t* pA1 = A + (size_t)(tm * 128 + (2 * w + 1) * 16 + lane16) * KK + quad * 8;
    const bf16_t* pB0 = B + (size_t)(tn * 128 + (2 * w + 0) * 16 + lane16) * KK + quad * 8;
    const bf16_t* pB1 = B + (size_t)(tn * 128 + (2 * w + 1) * 16 + lane16) * KK + quad * 8;

    bf16_t* wA0 = &ldsA[(2 * w + 0) * 512 + l * 8];
    bf16_t* wA1 = &ldsA[(2 * w + 1) * 512 + l * 8];
    bf16_t* wB0 = &ldsB[(2 * w + 0) * 512 + l * 8];
    bf16_t* wB1 = &ldsB[(2 * w + 1) * 512 + l * 8];
    const bf16_t* rA = &ldsA[wm * 4 * 512 + l * 8];
    const bf16_t* rB = &ldsB[wn * 4 * 512 + l * 8];

    f32x4 acc[4][4];
    for (int i = 0; i < 4; i++)
        for (int j = 0; j < 4; j++) acc[i][j] = (f32x4){0.f, 0.f, 0.f, 0.f};

    for (int k0 = 0; k0 < KK; k0 += 32) {
        uint4 a0 = *(const uint4*)pA0; pA0 += 32;
        uint4 a1 = *(const uint4*)pA1; pA1 += 32;
        uint4 b0 = *(const uint4*)pB0; pB0 += 32;
        uint4 b1 = *(const uint4*)pB1; pB1 += 32;
        __syncthreads();
        *(uint4*)wA0 = a0; *(uint4*)wA1 = a1;
        *(uint4*)wB0 = b0; *(uint4*)wB1 = b1;
        __syncthreads();
        bf16x8 af[4], bfr[4];
        for (int i = 0; i < 4; i++) af[i]  = *(const bf16x8*)(rA + i * 512);
        for (int j = 0; j < 4; j++) bfr[j] = *(const bf16x8*)(rB + j * 512);
        for (int i = 0; i < 4; i++)
            for (int j = 0; j < 4; j++)
                acc[i][j] = __builtin_amdgcn_mfma_f32_16x16x32_bf16(af[i], bfr[j], acc[i][j], 0, 0, 0);
    }

    const int mbase = tm * 128 + wm * 64;
    const int nbase = tn * 128 + wn * 64;
    for (int i = 0; i < 4; i++) {
        for (int j = 0; j < 4; j++) {
            const int n  = nbase + j * 16 + lane16;
            const int m0 = mbase + i * 16 + quad * 4;
            if (MODE == 0) {
                const int h = n >> 7, d = n & 127;
                for (int r = 0; r < 4; r++) {
                    const int m = m0 + r, b = m >> 11, s = m & 2047;
                    ((bf16_t*)Cout)[(((size_t)(b * NH + h) * SEQ + s) * HD) + d] = (bf16_t)acc[i][j][r];
                }
            } else if (MODE == 2) {
                const int h = n >> 7, d = n & 127;
                const int b = m0 >> 11, s = m0 & 2047;
                union { bf16_t h4[4]; ushort4 u; } tv;
                for (int r = 0; r < 4; r++) tv.h4[r] = (bf16_t)acc[i][j][r];
                *(ushort4*)((bf16_t*)Cout + ((size_t)(b * NH + h) * HD + d) * SEQ + s) = tv.u;
            } else {
                for (int r = 0; r < 4; r++) {
                    const int m = m0 + r;
                    ((float*)Cout)[(size_t)m * NN + n] = acc[i][j][r];
                }
            }
        }
    }
}

// ---------------------------------------------------------------- RoPE in place on Q,K [b,h,s,d]
__global__ __launch_bounds__(256) void rope_kernel(bf16_t* __restrict__ Q,
                                                   bf16_t* __restrict__ K,
                                                   const int* __restrict__ pos) {
    int gid = blockIdx.x * 256 + threadIdx.x;   // 2*16*2048*64 threads
    int i  = gid & 63;
    int s  = (gid >> 6) & 2047;
    int bh = gid >> 17;                          // 0..31
    int b  = bh >> 4;
    float p = (float)pos[b * SEQ + s];
    float freq = exp2f(-(float)i * 0.20762050593045857f); // i*2/128*log2(10000)
    float ang = p * freq;
    float sn, cs;
    sincosf(ang, &sn, &cs);
    size_t base = ((size_t)bh * SEQ + s) * HD + 2 * i;
    {
        float q1 = (float)Q[base], q2 = (float)Q[base + 1];
        Q[base]     = (bf16_t)(q1 * cs - q2 * sn);
        Q[base + 1] = (bf16_t)(q1 * sn + q2 * cs);
    }
    {
        float k1 = (float)K[base], k2 = (float)K[base + 1];
        K[base]     = (bf16_t)(k1 * cs - k2 * sn);
        K[base + 1] = (bf16_t)(k1 * sn + k2 * cs);
    }
}

// ---------------------------------------------------------------- causal flash attention
// Q,K: [b,h,s,d] bf16 (rope applied).  Vt: [b,h,d,s] bf16.  ctx out: [b,s,h*d] bf16.
__global__ __launch_bounds__(256) void attn_kernel(const bf16_t* __restrict__ Q,
                                                   const bf16_t* __restrict__ K,
                                                   const bf16_t* __restrict__ Vt,
                                                   bf16_t* __restrict__ ctx) {
    const int qb = gridDim.x - 1 - blockIdx.x;  // heavy blocks dispatch first
    const int h = blockIdx.y, b = blockIdx.z;
    const int bh = b * NH + h;
    const bf16_t* Qh = Q  + (size_t)bh * SEQ * HD;
    const bf16_t* Kh = K  + (size_t)bh * SEQ * HD;
    const bf16_t* Vh = Vt + (size_t)bh * HD * SEQ;

    const int tid = threadIdx.x;
    const int w = tid >> 6, l = tid & 63;
    const int lane16 = l & 15, quad = l >> 4;
    const int q0 = qb * 64 + w * 16;

    // K tile: 8 frags (nt*4+kc): slot l = (key nt*16+(l&15), dims kc*32+(l>>4)*8 ..+8)
    __shared__ bf16_t kt[8 * 512];
    // V tile: 8 frags (dt): slot l = (dim dt*16+(l&15), keys (l>>4)*8 ..+8)
    __shared__ bf16_t vt[8 * 512];
    // per-wave P buffer, A-operand fragment-native (16 q x 32 k)
    __shared__ bf16_t pbuf[4][512];

    // Q fragments (A-operand), dims t*32 + quad*8 ..+8
    bf16x8 qf[4];
    {
        const bf16_t* qrow = Qh + (size_t)(q0 + lane16) * HD + quad * 8;
        for (int t = 0; t < 4; t++) qf[t] = *(const bf16x8*)(qrow + t * 32);
    }

    f32x4 o[8];
    for (int dt = 0; dt < 8; dt++) o[dt] = (f32x4){0.f, 0.f, 0.f, 0.f};
    float m_r[4], l_r[4];
    for (int r = 0; r < 4; r++) { m_r[r] = -INFINITY; l_r[r] = 0.f; }

    const float scale = 0.08838834764831845f; // 1/sqrt(128)
    const int kb_end = qb * 2 + 2;

    for (int kb = 0; kb < kb_end; kb++) {
        __syncthreads();
        // stage K and V^T tiles (each thread: 2 K frags + 2 V frags, 16B each)
        for (int ii = 0; ii < 2; ii++) {
            const int fk = w * 2 + ii;
            const int nt = fk >> 2, kc = fk & 3;
            const int key = kb * 32 + nt * 16 + lane16;
            const int dim = kc * 32 + quad * 8;
            *(uint4*)&kt[fk * 512 + l * 8] = *(const uint4*)(Kh + (size_t)key * HD + dim);
            const int vdim = fk * 16 + lane16;
            *(uint4*)&vt[fk * 512 + l * 8] = *(const uint4*)(Vh + (size_t)vdim * SEQ + kb * 32 + quad * 8);
        }
        __syncthreads();
        if (q0 + 15 < kb * 32) continue;   // fully-masked tile for this wave

        // S = Q K^T for 32 keys (2 col-tiles of 16)
        f32x4 sacc[2];
        sacc[0] = (f32x4){0.f, 0.f, 0.f, 0.f};
        sacc[1] = (f32x4){0.f, 0.f, 0.f, 0.f};
        for (int nt = 0; nt < 2; nt++)
            for (int kc = 0; kc < 4; kc++) {
                bf16x8 kf = *(const bf16x8*)&kt[(nt * 4 + kc) * 512 + l * 8];
                sacc[nt] = __builtin_amdgcn_mfma_f32_16x16x32_bf16(qf[kc], kf, sacc[nt], 0, 0, 0);
            }
        // scale + causal mask
        for (int nt = 0; nt < 2; nt++)
            for (int r = 0; r < 4; r++) {
                const int qg = q0 + quad * 4 + r;
                const int kg = kb * 32 + nt * 16 + lane16;
                const float v = sacc[nt][r] * scale;
                sacc[nt][r] = (kg <= qg) ? v : -INFINITY;
            }
        // online softmax per row (rows live across 16 lanes of the quad)
        float alpha[4];
        for (int r = 0; r < 4; r++) {
            float v = fmaxf(sacc[0][r], sacc[1][r]);
            for (int off = 1; off < 16; off <<= 1) v = fmaxf(v, __shfl_xor(v, off, 64));
            const float mnew = fmaxf(m_r[r], v);
            alpha[r] = __expf(m_r[r] - mnew);
            float s = 0.f;
            for (int nt = 0; nt < 2; nt++) {
                const float e0 = __expf(sacc[nt][r] - mnew);  // exp(-inf)=0 for masked
                const int kl = nt * 16 + lane16;
                // A-operand slot: l' = (kl>>3)*16 + qrow ; elem j = kl&7
                pbuf[w][((2 * nt + (lane16 >> 3)) * 16 + quad * 4 + r) * 8 + (lane16 & 7)] = (bf16_t)e0;
                s += e0;
            }
            for (int off = 1; off < 16; off <<= 1) s += __shfl_xor(s, off, 64);
            l_r[r] = l_r[r] * alpha[r] + s;
            m_r[r] = mnew;
        }
        // rescale O, then O += P V   (intra-wave LDS ops are in-order)
        for (int dt = 0; dt < 8; dt++)
            for (int r = 0; r < 4; r++) o[dt][r] *= alpha[r];
        bf16x8 pf = *(const bf16x8*)&pbuf[w][l * 8];
        for (int dt = 0; dt < 8; dt++) {
            bf16x8 vf = *(const bf16x8*)&vt[dt * 512 + l * 8];
            o[dt] = __builtin_amdgcn_mfma_f32_16x16x32_bf16(pf, vf, o[dt], 0, 0, 0);
        }
    }

    // epilogue: ctx[b, s=q, h*128 + d]
    for (int r = 0; r < 4; r++) {
        const int qg = q0 + quad * 4 + r;
        const float inv = 1.0f / l_r[r];
        for (int dt = 0; dt < 8; dt++) {
            ctx[((size_t)(b * SEQ + qg)) * (NH * HD) + h * HD + dt * 16 + lane16] =
                (bf16_t)(o[dt][r] * inv);
        }
    }
}

// ---------------------------------------------------------------- launch
extern "C" void kernel_launch(void* const* d_in, const int* in_sizes, int n_in,
                              void* d_out, int out_size, void* d_ws, size_t ws_size,
                              hipStream_t stream) {
    const float* x  = (const float*)d_in[0];
    const int* pos  = (const int*)d_in[1];
    const float* Wq = (const float*)d_in[2];
    const float* Wk = (const float*)d_in[3];
    const float* Wv = (const float*)d_in[4];
    const float* Wo = (const float*)d_in[5];

    char* ws = (char*)d_ws;
    bf16_t* xb  = (bf16_t*)(ws);
    bf16_t* wqb = (bf16_t*)(ws + (16u << 20));
    bf16_t* wkb = (bf16_t*)(ws + (24u << 20));
    bf16_t* wvb = (bf16_t*)(ws + (32u << 20));
    bf16_t* wob = (bf16_t*)(ws + (40u << 20));
    bf16_t* Qb  = (bf16_t*)(ws + (48u << 20));
    bf16_t* Kb  = (bf16_t*)(ws + (64u << 20));
    bf16_t* Vt  = (bf16_t*)(ws + (80u << 20));
    bf16_t* ctx = (bf16_t*)(ws + (96u << 20));

    cast_f32_bf16<<<8192, 256, 0, stream>>>(x,  xb,  2097152);
    cast_f32_bf16<<<4096, 256, 0, stream>>>(Wq, wqb, 1048576);
    cast_f32_bf16<<<4096, 256, 0, stream>>>(Wk, wkb, 1048576);
    cast_f32_bf16<<<4096, 256, 0, stream>>>(Wv, wvb, 1048576);
    cast_f32_bf16<<<4096, 256, 0, stream>>>(Wo, wob, 1048576);

    dim3 gg(NN / 128, MM / 128);
    gemm_bt<0><<<gg, 256, 0, stream>>>(xb, wqb, (void*)Qb);
    gemm_bt<0><<<gg, 256, 0, stream>>>(xb, wkb, (void*)Kb);
    gemm_bt<2><<<gg, 256, 0, stream>>>(xb, wvb, (void*)Vt);

    rope_kernel<<<16384, 256, 0, stream>>>(Qb, Kb, pos);

    dim3 ga(SEQ / 64, NH, 2);
    attn_kernel<<<ga, 256, 0, stream>>>(Qb, Kb, Vt, ctx);

    gemm_bt<1><<<gg, 256, 0, stream>>>(ctx, wob, d_out);
}

// Round 2
// 535.747 us; speedup vs baseline: 1.2971x; 1.2971x over previous
//
#include <hip/hip_runtime.h>
#include <cstdint>
#include <cstddef>

typedef __bf16 bf16_t;
typedef __bf16 bf16x8 __attribute__((ext_vector_type(8)));
typedef float  f32x4  __attribute__((ext_vector_type(4)));

#define SEQ 2048
#define NH  16
#define HD  128
#define MM  4096   // b*s rows
#define KK  2048
#define NN  2048

// async global->LDS, 16B per lane, LDS dest = wave-uniform base + lane*16
#define ASYNC16(g, l) __builtin_amdgcn_global_load_lds( \
    (const __attribute__((address_space(1))) void*)(g), \
    (__attribute__((address_space(3))) void*)(l), 16, 0, 0)

// ---------------------------------------------------------------- cast fp32->bf16
__global__ __launch_bounds__(256) void cast_f32_bf16(const float* __restrict__ src,
                                                     bf16_t* __restrict__ dst, int n4) {
    int i = blockIdx.x * 256 + threadIdx.x;
    if (i >= n4) return;
    float4 v = ((const float4*)src)[i];
    union { bf16_t h[4]; uint2 u; } t;
    t.h[0] = (bf16_t)v.x; t.h[1] = (bf16_t)v.y;
    t.h[2] = (bf16_t)v.z; t.h[3] = (bf16_t)v.w;
    ((uint2*)dst)[i] = t.u;
}

// ---------------------------------------------------------------- GEMM  C = A * B^T
// A: [MM,KK] bf16 row-major; B: [NN,KK] bf16 row-major (weights are [out,in]).
// MODE 0: bf16 out scattered to Q/K layout [b,h,s,d]
// MODE 2: bf16 out to V^T layout [b,h,d,s]
// MODE 1: fp32 out row-major [MM,NN]
template<int MODE>
__global__ __launch_bounds__(256) void gemm_bt(const bf16_t* __restrict__ A,
                                               const bf16_t* __restrict__ B,
                                               void* __restrict__ Cout) {
    // fragment-native LDS: frag f (16 rows x 32 k) stored as 64 slots of 16B,
    // slot l <-> (row = f*16 + (l&15), k-chunk = (l>>4)*8) — lane-contiguous.
    __shared__ bf16_t ldsA[8 * 512];
    __shared__ bf16_t ldsB[8 * 512];

    const int tid = threadIdx.x;
    const int w = tid >> 6, l = tid & 63;
    const int lane16 = l & 15, quad = l >> 4;
    const int tm = blockIdx.y, tn = blockIdx.x;
    const int wm = w >> 1, wn = w & 1;

    const bf16_t* pA0 = A + (size_t)(tm * 128 + (2 * w + 0) * 16 + lane16) * KK + quad * 8;
    const bf16_t* pA1 = A + (size_t)(tm * 128 + (2 * w + 1) * 16 + lane16) * KK + quad * 8;
    const bf16_t* pB0 = B + (size_t)(tn * 128 + (2 * w + 0) * 16 + lane16) * KK + quad * 8;
    const bf16_t* pB1 = B + (size_t)(tn * 128 + (2 * w + 1) * 16 + lane16) * KK + quad * 8;

    bf16_t* wA0 = &ldsA[(2 * w + 0) * 512];   // wave-uniform LDS bases
    bf16_t* wA1 = &ldsA[(2 * w + 1) * 512];
    bf16_t* wB0 = &ldsB[(2 * w + 0) * 512];
    bf16_t* wB1 = &ldsB[(2 * w + 1) * 512];
    const bf16_t* rA = &ldsA[wm * 4 * 512 + l * 8];
    const bf16_t* rB = &ldsB[wn * 4 * 512 + l * 8];

    f32x4 acc[4][4];
    for (int i = 0; i < 4; i++)
        for (int j = 0; j < 4; j++) acc[i][j] = (f32x4){0.f, 0.f, 0.f, 0.f};

    for (int k0 = 0; k0 < KK; k0 += 32) {
        __syncthreads();
        ASYNC16(pA0, wA0); ASYNC16(pA1, wA1);
        ASYNC16(pB0, wB0); ASYNC16(pB1, wB1);
        pA0 += 32; pA1 += 32; pB0 += 32; pB1 += 32;
        __syncthreads();
        bf16x8 af[4], bfr[4];
        for (int i = 0; i < 4; i++) af[i]  = *(const bf16x8*)(rA + i * 512);
        for (int j = 0; j < 4; j++) bfr[j] = *(const bf16x8*)(rB + j * 512);
        for (int i = 0; i < 4; i++)
            for (int j = 0; j < 4; j++)
                acc[i][j] = __builtin_amdgcn_mfma_f32_16x16x32_bf16(af[i], bfr[j], acc[i][j], 0, 0, 0);
    }

    const int mbase = tm * 128 + wm * 64;
    const int nbase = tn * 128 + wn * 64;
    for (int i = 0; i < 4; i++) {
        for (int j = 0; j < 4; j++) {
            const int n  = nbase + j * 16 + lane16;
            const int m0 = mbase + i * 16 + quad * 4;
            if (MODE == 0) {
                const int h = n >> 7, d = n & 127;
                for (int r = 0; r < 4; r++) {
                    const int m = m0 + r, b = m >> 11, s = m & 2047;
                    ((bf16_t*)Cout)[(((size_t)(b * NH + h) * SEQ + s) * HD) + d] = (bf16_t)acc[i][j][r];
                }
            } else if (MODE == 2) {
                const int h = n >> 7, d = n & 127;
                const int b = m0 >> 11, s = m0 & 2047;
                union { bf16_t h4[4]; ushort4 u; } tv;
                for (int r = 0; r < 4; r++) tv.h4[r] = (bf16_t)acc[i][j][r];
                *(ushort4*)((bf16_t*)Cout + ((size_t)(b * NH + h) * HD + d) * SEQ + s) = tv.u;
            } else {
                for (int r = 0; r < 4; r++) {
                    const int m = m0 + r;
                    ((float*)Cout)[(size_t)m * NN + n] = acc[i][j][r];
                }
            }
        }
    }
}

// ---------------------------------------------------------------- RoPE in place on Q,K [b,h,s,d]
__global__ __launch_bounds__(256) void rope_kernel(bf16_t* __restrict__ Q,
                                                   bf16_t* __restrict__ K,
                                                   const int* __restrict__ pos) {
    int gid = blockIdx.x * 256 + threadIdx.x;   // 2*16*2048*64 threads
    int i  = gid & 63;
    int s  = (gid >> 6) & 2047;
    int bh = gid >> 17;                          // 0..31
    int b  = bh >> 4;
    float p = (float)pos[b * SEQ + s];
    float freq = exp2f(-(float)i * 0.20762050593045857f); // i*2/128*log2(10000)
    float ang = p * freq;
    float sn, cs;
    sincosf(ang, &sn, &cs);
    size_t base = ((size_t)bh * SEQ + s) * HD + 2 * i;
    {
        float q1 = (float)Q[base], q2 = (float)Q[base + 1];
        Q[base]     = (bf16_t)(q1 * cs - q2 * sn);
        Q[base + 1] = (bf16_t)(q1 * sn + q2 * cs);
    }
    {
        float k1 = (float)K[base], k2 = (float)K[base + 1];
        K[base]     = (bf16_t)(k1 * cs - k2 * sn);
        K[base + 1] = (bf16_t)(k1 * sn + k2 * cs);
    }
}

// ---------------------------------------------------------------- causal flash attention
// Q,K: [b,h,s,d] bf16 (rope applied).  Vt: [b,h,d,s] bf16.  ctx out: [b,s,h*d] bf16.
// Block = 4 waves x 16 q-rows = 64-row q-tile; block bt processes q-tiles {bt, 31-bt}
// (perfect causal load balance: (t+1) + (32-t) = 33 key-tile iterations each).
// BK = 64 keys per iteration, async staged; mask applied only on the diagonal tile.
__global__ __launch_bounds__(256) void attn_kernel(const bf16_t* __restrict__ Q,
                                                   const bf16_t* __restrict__ K,
                                                   const bf16_t* __restrict__ Vt,
                                                   bf16_t* __restrict__ ctx) {
    const int bt = blockIdx.x;                  // 0..15
    const int h = blockIdx.y, b = blockIdx.z;
    const int bh = b * NH + h;
    const bf16_t* Qh = Q  + (size_t)bh * SEQ * HD;
    const bf16_t* Kh = K  + (size_t)bh * SEQ * HD;
    const bf16_t* Vh = Vt + (size_t)bh * HD * SEQ;

    const int tid = threadIdx.x;
    const int w = tid >> 6, l = tid & 63;
    const int lane16 = l & 15, quad = l >> 4;

    // K tile (64 keys x 128 dims): 16 frags f=nt*4+kc: slot l=(key nt*16+(l&15), dim kc*32+(l>>4)*8)
    __shared__ bf16_t kt[16 * 512];
    // V^T tile (128 dims x 64 keys): 16 frags f=dt*2+kk: slot l=(dim dt*16+(l&15), key kk*32+(l>>4)*8)
    __shared__ bf16_t vt[16 * 512];
    // per-wave P (16 q x 64 k), A-operand layout, 2 frags
    __shared__ bf16_t pbuf[4][1024];

    const float scale = 0.08838834764831845f; // 1/sqrt(128)

    for (int half = 0; half < 2; half++) {
        const int qt = half ? (31 - bt) : bt;   // q-tile of 64 rows
        const int q0 = qt * 64 + w * 16;

        // Q fragments (A-operand): dims kc*32 + quad*8
        bf16x8 qf[4];
        {
            const bf16_t* qrow = Qh + (size_t)(q0 + lane16) * HD + quad * 8;
            for (int kc = 0; kc < 4; kc++) qf[kc] = *(const bf16x8*)(qrow + kc * 32);
        }

        f32x4 o[8];
        for (int dt = 0; dt < 8; dt++) o[dt] = (f32x4){0.f, 0.f, 0.f, 0.f};
        float m_r[4], l_r[4];
        for (int r = 0; r < 4; r++) { m_r[r] = -INFINITY; l_r[r] = 0.f; }

        for (int kb = 0; kb <= qt; kb++) {
            const int k0 = kb * 64;
            __syncthreads();    // prior iteration's LDS reads complete
            // async stage: each wave stages 4 K frags + 4 V frags (1 KB each)
            for (int ii = 0; ii < 4; ii++) {
                const int f = w * 4 + ii;
                const int nt = f >> 2, kc = f & 3;
                ASYNC16(Kh + (size_t)(k0 + nt * 16 + lane16) * HD + kc * 32 + quad * 8,
                        &kt[f * 512]);
                const int dt = f >> 1, kk = f & 1;
                ASYNC16(Vh + (size_t)(dt * 16 + lane16) * SEQ + k0 + kk * 32 + quad * 8,
                        &vt[f * 512]);
            }
            __syncthreads();    // drains vmcnt -> tiles visible

            // S = Q K^T : 16 rows x 64 keys (4 col-tiles)
            f32x4 sacc[4];
            for (int nt = 0; nt < 4; nt++) sacc[nt] = (f32x4){0.f, 0.f, 0.f, 0.f};
            for (int nt = 0; nt < 4; nt++)
                for (int kc = 0; kc < 4; kc++) {
                    bf16x8 kf = *(const bf16x8*)&kt[(nt * 4 + kc) * 512 + l * 8];
                    sacc[nt] = __builtin_amdgcn_mfma_f32_16x16x32_bf16(qf[kc], kf, sacc[nt], 0, 0, 0);
                }
            // scale (+ mask only on the diagonal tile; kb < qt tiles are fully visible)
            if (kb == qt) {
                for (int nt = 0; nt < 4; nt++)
                    for (int r = 0; r < 4; r++) {
                        const int qg = q0 + quad * 4 + r;
                        const int kg = k0 + nt * 16 + lane16;
                        sacc[nt][r] = (kg <= qg) ? sacc[nt][r] * scale : -INFINITY;
                    }
            } else {
                for (int nt = 0; nt < 4; nt++)
                    for (int r = 0; r < 4; r++) sacc[nt][r] *= scale;
            }
            // online softmax (row = quad*4+r across 16 lanes)
            float alpha[4];
            for (int r = 0; r < 4; r++) {
                float v = fmaxf(fmaxf(sacc[0][r], sacc[1][r]), fmaxf(sacc[2][r], sacc[3][r]));
                for (int off = 1; off < 16; off <<= 1) v = fmaxf(v, __shfl_xor(v, off, 64));
                const float mnew = fmaxf(m_r[r], v);
                const float a = __expf(m_r[r] - mnew);
                alpha[r] = a;
                float ssum = 0.f;
                for (int nt = 0; nt < 4; nt++) {
                    const float e = __expf(sacc[nt][r] - mnew);  // exp(-inf)=0 masked
                    const int kk = nt >> 1, ntl = nt & 1;
                    pbuf[w][kk * 512 +
                            ((2 * ntl + (lane16 >> 3)) * 16 + quad * 4 + r) * 8 +
                            (lane16 & 7)] = (bf16_t)e;
                    ssum += e;
                }
                for (int off = 1; off < 16; off <<= 1) ssum += __shfl_xor(ssum, off, 64);
                l_r[r] = l_r[r] * a + ssum;
                m_r[r] = mnew;
            }
            // rescale O then O += P V  (intra-wave LDS ordering is safe)
            for (int dt = 0; dt < 8; dt++)
                for (int r = 0; r < 4; r++) o[dt][r] *= alpha[r];
            for (int kk = 0; kk < 2; kk++) {
                bf16x8 pf = *(const bf16x8*)&pbuf[w][kk * 512 + l * 8];
                for (int dt = 0; dt < 8; dt++) {
                    bf16x8 vf = *(const bf16x8*)&vt[(dt * 2 + kk) * 512 + l * 8];
                    o[dt] = __builtin_amdgcn_mfma_f32_16x16x32_bf16(pf, vf, o[dt], 0, 0, 0);
                }
            }
        }

        // epilogue: ctx[b, s=q, h*128 + d]
        for (int r = 0; r < 4; r++) {
            const int qg = q0 + quad * 4 + r;
            const float inv = 1.0f / l_r[r];
            for (int dt = 0; dt < 8; dt++) {
                ctx[((size_t)(b * SEQ + qg)) * (NH * HD) + h * HD + dt * 16 + lane16] =
                    (bf16_t)(o[dt][r] * inv);
            }
        }
        __syncthreads();   // half-boundary: protect LDS reuse
    }
}

// ---------------------------------------------------------------- launch
extern "C" void kernel_launch(void* const* d_in, const int* in_sizes, int n_in,
                              void* d_out, int out_size, void* d_ws, size_t ws_size,
                              hipStream_t stream) {
    const float* x  = (const float*)d_in[0];
    const int* pos  = (const int*)d_in[1];
    const float* Wq = (const float*)d_in[2];
    const float* Wk = (const float*)d_in[3];
    const float* Wv = (const float*)d_in[4];
    const float* Wo = (const float*)d_in[5];

    char* ws = (char*)d_ws;
    bf16_t* xb  = (bf16_t*)(ws);
    bf16_t* wqb = (bf16_t*)(ws + (16u << 20));
    bf16_t* wkb = (bf16_t*)(ws + (24u << 20));
    bf16_t* wvb = (bf16_t*)(ws + (32u << 20));
    bf16_t* wob = (bf16_t*)(ws + (40u << 20));
    bf16_t* Qb  = (bf16_t*)(ws + (48u << 20));
    bf16_t* Kb  = (bf16_t*)(ws + (64u << 20));
    bf16_t* Vt  = (bf16_t*)(ws + (80u << 20));
    bf16_t* ctx = (bf16_t*)(ws + (96u << 20));

    cast_f32_bf16<<<8192, 256, 0, stream>>>(x,  xb,  2097152);
    cast_f32_bf16<<<4096, 256, 0, stream>>>(Wq, wqb, 1048576);
    cast_f32_bf16<<<4096, 256, 0, stream>>>(Wk, wkb, 1048576);
    cast_f32_bf16<<<4096, 256, 0, stream>>>(Wv, wvb, 1048576);
    cast_f32_bf16<<<4096, 256, 0, stream>>>(Wo, wob, 1048576);

    dim3 gg(NN / 128, MM / 128);
    gemm_bt<0><<<gg, 256, 0, stream>>>(xb, wqb, (void*)Qb);
    gemm_bt<0><<<gg, 256, 0, stream>>>(xb, wkb, (void*)Kb);
    gemm_bt<2><<<gg, 256, 0, stream>>>(xb, wvb, (void*)Vt);

    rope_kernel<<<16384, 256, 0, stream>>>(Qb, Kb, pos);

    dim3 ga(16, NH, 2);
    attn_kernel<<<ga, 256, 0, stream>>>(Qb, Kb, Vt, ctx);

    gemm_bt<1><<<gg, 256, 0, stream>>>(ctx, wob, d_out);
}

// Round 3
// 479.914 us; speedup vs baseline: 1.4480x; 1.1163x over previous
//
#include <hip/hip_runtime.h>
#include <cstdint>
#include <cstddef>

typedef __bf16 bf16_t;
typedef __bf16 bf16x8 __attribute__((ext_vector_type(8)));
typedef float  f32x4  __attribute__((ext_vector_type(4)));

#define SEQ 2048
#define NH  16
#define HD  128
#define MM  4096   // b*s rows
#define KK  2048

// async global->LDS, 16B per lane, LDS dest = wave-uniform base + lane*16
#define ASYNC16(g, l) __builtin_amdgcn_global_load_lds( \
    (const __attribute__((address_space(1))) void*)(g), \
    (__attribute__((address_space(3))) void*)(l), 16, 0, 0)

// ---------------------------------------------------------------- cast fp32->bf16 (x)
__global__ __launch_bounds__(256) void cast_f32_bf16(const float* __restrict__ src,
                                                     bf16_t* __restrict__ dst, int n4) {
    int i = blockIdx.x * 256 + threadIdx.x;
    if (i >= n4) return;
    float4 v = ((const float4*)src)[i];
    union { bf16_t h[4]; uint2 u; } t;
    t.h[0] = (bf16_t)v.x; t.h[1] = (bf16_t)v.y;
    t.h[2] = (bf16_t)v.z; t.h[3] = (bf16_t)v.w;
    ((uint2*)dst)[i] = t.u;
}

// ---------------------------------------------------------------- cast all 4 weights
// Wq,Wk,Wv -> contiguous wqkv [6144,2048]; Wo -> wob. 4 x 1M float4 groups.
__global__ __launch_bounds__(256) void cast_w4(const float* __restrict__ Wq,
                                               const float* __restrict__ Wk,
                                               const float* __restrict__ Wv,
                                               const float* __restrict__ Wo,
                                               bf16_t* __restrict__ wqkv,
                                               bf16_t* __restrict__ wob) {
    int i = blockIdx.x * 256 + threadIdx.x;     // 0..4M-1
    int sel = i >> 20;
    int off = i & 0xFFFFF;
    const float* src = (sel == 0) ? Wq : (sel == 1) ? Wk : (sel == 2) ? Wv : Wo;
    bf16_t* dst = (sel < 3) ? (wqkv + (size_t)sel * 4194304) : wob;
    float4 v = ((const float4*)src)[off];
    union { bf16_t h[4]; uint2 u; } t;
    t.h[0] = (bf16_t)v.x; t.h[1] = (bf16_t)v.y;
    t.h[2] = (bf16_t)v.z; t.h[3] = (bf16_t)v.w;
    ((uint2*)dst)[off] = t.u;
}

// ---------------------------------------------------------------- GEMM  C = A * B^T
// A: [MM,KK] bf16 row-major; B: [N,KK] bf16 row-major (weights are [out,in]).
// MODE 3: fused QKV (N=6144): n<2048 -> Q [b,h,s,d]; <4096 -> K [b,h,s,d]; else V^T [b,h,d,s]
// MODE 1: fp32 out row-major [MM,2048]
template<int MODE>
__global__ __launch_bounds__(256) void gemm_bt(const bf16_t* __restrict__ A,
                                               const bf16_t* __restrict__ B,
                                               void* __restrict__ Cout,
                                               bf16_t* __restrict__ Kout,
                                               bf16_t* __restrict__ Vout) {
    // fragment-native LDS: frag f (16 rows x 32 k) = 64 slots of 16B, lane-contiguous.
    __shared__ bf16_t ldsA[8 * 512];
    __shared__ bf16_t ldsB[8 * 512];

    const int tid = threadIdx.x;
    const int w = tid >> 6, l = tid & 63;
    const int lane16 = l & 15, quad = l >> 4;
    const int tm = blockIdx.y, tn = blockIdx.x;
    const int wm = w >> 1, wn = w & 1;

    const bf16_t* pA0 = A + (size_t)(tm * 128 + (2 * w + 0) * 16 + lane16) * KK + quad * 8;
    const bf16_t* pA1 = A + (size_t)(tm * 128 + (2 * w + 1) * 16 + lane16) * KK + quad * 8;
    const bf16_t* pB0 = B + (size_t)(tn * 128 + (2 * w + 0) * 16 + lane16) * KK + quad * 8;
    const bf16_t* pB1 = B + (size_t)(tn * 128 + (2 * w + 1) * 16 + lane16) * KK + quad * 8;

    bf16_t* wA0 = &ldsA[(2 * w + 0) * 512];   // wave-uniform LDS bases
    bf16_t* wA1 = &ldsA[(2 * w + 1) * 512];
    bf16_t* wB0 = &ldsB[(2 * w + 0) * 512];
    bf16_t* wB1 = &ldsB[(2 * w + 1) * 512];
    const bf16_t* rA = &ldsA[wm * 4 * 512 + l * 8];
    const bf16_t* rB = &ldsB[wn * 4 * 512 + l * 8];

    f32x4 acc[4][4];
    for (int i = 0; i < 4; i++)
        for (int j = 0; j < 4; j++) acc[i][j] = (f32x4){0.f, 0.f, 0.f, 0.f};

    for (int k0 = 0; k0 < KK; k0 += 32) {
        __syncthreads();
        ASYNC16(pA0, wA0); ASYNC16(pA1, wA1);
        ASYNC16(pB0, wB0); ASYNC16(pB1, wB1);
        pA0 += 32; pA1 += 32; pB0 += 32; pB1 += 32;
        __syncthreads();
        bf16x8 af[4], bfr[4];
        for (int i = 0; i < 4; i++) af[i]  = *(const bf16x8*)(rA + i * 512);
        for (int j = 0; j < 4; j++) bfr[j] = *(const bf16x8*)(rB + j * 512);
        for (int i = 0; i < 4; i++)
            for (int j = 0; j < 4; j++)
                acc[i][j] = __builtin_amdgcn_mfma_f32_16x16x32_bf16(af[i], bfr[j], acc[i][j], 0, 0, 0);
    }

    const int mbase = tm * 128 + wm * 64;
    const int nbase = tn * 128 + wn * 64;
    for (int i = 0; i < 4; i++) {
        for (int j = 0; j < 4; j++) {
            const int n  = nbase + j * 16 + lane16;
            const int m0 = mbase + i * 16 + quad * 4;
            if (MODE == 3) {
                const int sel = n >> 11;          // uniform per block
                const int n2 = n & 2047;
                const int h = n2 >> 7, d = n2 & 127;
                if (sel < 2) {
                    bf16_t* dst = (sel == 0) ? (bf16_t*)Cout : Kout;
                    for (int r = 0; r < 4; r++) {
                        const int m = m0 + r, b = m >> 11, s = m & 2047;
                        dst[(((size_t)(b * NH + h) * SEQ + s) * HD) + d] = (bf16_t)acc[i][j][r];
                    }
                } else {
                    const int b = m0 >> 11, s = m0 & 2047;
                    union { bf16_t h4[4]; ushort4 u; } tv;
                    for (int r = 0; r < 4; r++) tv.h4[r] = (bf16_t)acc[i][j][r];
                    *(ushort4*)(Vout + ((size_t)(b * NH + h) * HD + d) * SEQ + s) = tv.u;
                }
            } else {
                for (int r = 0; r < 4; r++) {
                    const int m = m0 + r;
                    ((float*)Cout)[(size_t)m * 2048 + n] = acc[i][j][r];
                }
            }
        }
    }
}

// ---------------------------------------------------------------- RoPE in place; Q pre-scaled by 1/sqrt(d)
__global__ __launch_bounds__(256) void rope_kernel(bf16_t* __restrict__ Q,
                                                   bf16_t* __restrict__ K,
                                                   const int* __restrict__ pos) {
    int gid = blockIdx.x * 256 + threadIdx.x;   // 2*16*2048*64 threads
    int i  = gid & 63;
    int s  = (gid >> 6) & 2047;
    int bh = gid >> 17;                          // 0..31
    int b  = bh >> 4;
    float p = (float)pos[b * SEQ + s];
    float freq = exp2f(-(float)i * 0.20762050593045857f); // i*2/128*log2(10000)
    float ang = p * freq;
    float sn, cs;
    sincosf(ang, &sn, &cs);
    const float scale = 0.08838834764831845f;    // 1/sqrt(128), folded into Q
    size_t base = ((size_t)bh * SEQ + s) * HD + 2 * i;
    {
        float q1 = (float)Q[base], q2 = (float)Q[base + 1];
        Q[base]     = (bf16_t)((q1 * cs - q2 * sn) * scale);
        Q[base + 1] = (bf16_t)((q1 * sn + q2 * cs) * scale);
    }
    {
        float k1 = (float)K[base], k2 = (float)K[base + 1];
        K[base]     = (bf16_t)(k1 * cs - k2 * sn);
        K[base + 1] = (bf16_t)(k1 * sn + k2 * cs);
    }
}

// ---------------------------------------------------------------- causal flash attention
// Q,K: [b,h,s,d] bf16 (rope applied, Q pre-scaled).  Vt: [b,h,d,s] bf16.  ctx: [b,s,h*d] bf16.
// Block = 4 waves x 16 q-rows = 64-row q-tile; block processes q-tiles {bt, 31-bt}
// (perfect causal balance: 33 key-tile iterations per block).
// Grid flat 512: bh = idx&31 (fastest) so each XCD keeps ~4 (b,h) K/V sets in its L2.
// S^T = K*Q^T so each lane owns one q-row (cheap softmax); K/V double-buffered,
// one barrier per iteration, loads for kb+1 in flight during compute on kb.
__global__ __launch_bounds__(256) void attn_kernel(const bf16_t* __restrict__ Q,
                                                   const bf16_t* __restrict__ K,
                                                   const bf16_t* __restrict__ Vt,
                                                   bf16_t* __restrict__ ctx) {
    const int flat = blockIdx.x;
    const int bh = flat & 31;
    const int bt = flat >> 5;                   // 0..15
    const int h = bh & 15, b = bh >> 4;
    const bf16_t* Qh = Q  + (size_t)bh * SEQ * HD;
    const bf16_t* Kh = K  + (size_t)bh * SEQ * HD;
    const bf16_t* Vh = Vt + (size_t)bh * HD * SEQ;

    const int tid = threadIdx.x;
    const int w = tid >> 6, l = tid & 63;
    const int lane16 = l & 15, quad = l >> 4;

    // K tile (64 keys x 128 d): frag f=nt*4+kc: slot l=(key nt*16+(l&15), d kc*32+(l>>4)*8)
    __shared__ bf16_t kt[2][16 * 512];
    // V^T tile (128 d x 64 keys): frag f=dt*2+kk: slot l=(d dt*16+(l&15), key kk*32+(l>>4)*8)
    __shared__ bf16_t vt[2][16 * 512];
    // per-wave P^T->A-operand buffer (16 q x 64 k), 2 frags
    __shared__ bf16_t pbuf[4][1024];

    for (int half = 0; half < 2; half++) {
        const int qt = half ? (31 - bt) : bt;   // q-tile of 64 rows
        const int q0 = qt * 64 + w * 16;

        // Q fragments: lane holds Q[q0+lane16][kc*32+quad*8 ..+8] (A- and B-operand layout)
        bf16x8 qf[4];
        {
            const bf16_t* qrow = Qh + (size_t)(q0 + lane16) * HD + quad * 8;
            for (int kc = 0; kc < 4; kc++) qf[kc] = *(const bf16x8*)(qrow + kc * 32);
        }

        f32x4 o[8];
        for (int dt = 0; dt < 8; dt++) o[dt] = (f32x4){0.f, 0.f, 0.f, 0.f};
        float m_s = -INFINITY, l_s = 0.f;       // per-lane: row q = q0 + lane16

        // prologue: stage kb=0 into buffer 0
        __syncthreads();                        // protect LDS from previous half's reads
        for (int ii = 0; ii < 4; ii++) {
            const int f = w * 4 + ii;
            const int nt = f >> 2, kc = f & 3;
            ASYNC16(Kh + (size_t)(nt * 16 + lane16) * HD + kc * 32 + quad * 8, &kt[0][f * 512]);
            const int dt = f >> 1, kk = f & 1;
            ASYNC16(Vh + (size_t)(dt * 16 + lane16) * SEQ + kk * 32 + quad * 8, &vt[0][f * 512]);
        }

        int cur = 0;
        for (int kb = 0; kb <= qt; kb++) {
            const int k0 = kb * 64;
            __syncthreads();                    // drains cur's loads (issued 1 iter ago)
            if (kb < qt) {                      // prefetch next tile into other buffer
                const int kn = k0 + 64;
                for (int ii = 0; ii < 4; ii++) {
                    const int f = w * 4 + ii;
                    const int nt = f >> 2, kc = f & 3;
                    ASYNC16(Kh + (size_t)(kn + nt * 16 + lane16) * HD + kc * 32 + quad * 8,
                            &kt[1 - cur][f * 512]);
                    const int dt = f >> 1, kk = f & 1;
                    ASYNC16(Vh + (size_t)(dt * 16 + lane16) * SEQ + kn + kk * 32 + quad * 8,
                            &vt[1 - cur][f * 512]);
                }
            }
            const bf16_t* ktc = kt[cur];
            const bf16_t* vtc = vt[cur];

            // S^T = K Q^T : row = key-in-tile (quad*4+r), col = q (lane16)
            f32x4 sacc[4];
            for (int nt = 0; nt < 4; nt++) sacc[nt] = (f32x4){0.f, 0.f, 0.f, 0.f};
            for (int nt = 0; nt < 4; nt++)
                for (int kc = 0; kc < 4; kc++) {
                    bf16x8 kf = *(const bf16x8*)&ktc[(nt * 4 + kc) * 512 + l * 8];
                    sacc[nt] = __builtin_amdgcn_mfma_f32_16x16x32_bf16(kf, qf[kc], sacc[nt], 0, 0, 0);
                }
            if (kb == qt) {   // diagonal tile mask: key_g > q_g -> -inf
                const int qg = q0 + lane16;
                for (int nt = 0; nt < 4; nt++)
                    for (int r = 0; r < 4; r++) {
                        const int kg = k0 + nt * 16 + quad * 4 + r;
                        if (kg > qg) sacc[nt][r] = -INFINITY;
                    }
            }
            // per-lane softmax for row q = q0 + lane16
            float rowmax = sacc[0][0];
            for (int nt = 0; nt < 4; nt++)
                for (int r = 0; r < 4; r++) rowmax = fmaxf(rowmax, sacc[nt][r]);
            rowmax = fmaxf(rowmax, __shfl_xor(rowmax, 16, 64));
            rowmax = fmaxf(rowmax, __shfl_xor(rowmax, 32, 64));
            const float mnew = fmaxf(m_s, rowmax);
            const float a = __expf(m_s - mnew);
            m_s = mnew;
            float ssum = 0.f;
            for (int nt = 0; nt < 4; nt++) {
                union { bf16_t h4[4]; uint2 u; } pk;
                for (int r = 0; r < 4; r++) {
                    const float e = __expf(sacc[nt][r] - mnew);   // exp(-inf)=0
                    ssum += e;
                    pk.h4[r] = (bf16_t)e;
                }
                // A-operand-native slot for (q=lane16, key=nt*16+quad*4+r)
                const int addr = (nt >> 1) * 512 +
                                 (((nt & 1) * 2 + (quad >> 1)) * 16 + lane16) * 8 +
                                 (quad & 1) * 4;
                *(uint2*)&pbuf[w][addr] = pk.u;
            }
            ssum += __shfl_xor(ssum, 16, 64);
            ssum += __shfl_xor(ssum, 32, 64);
            l_s = l_s * a + ssum;

            // redistribute alpha to O rows (O row q = quad*4+r), rescale, then O += P V
            float ar[4];
            for (int r = 0; r < 4; r++) ar[r] = __shfl(a, (quad << 2) | r, 16);
            for (int dt = 0; dt < 8; dt++)
                for (int r = 0; r < 4; r++) o[dt][r] *= ar[r];
            for (int kk = 0; kk < 2; kk++) {
                bf16x8 pf = *(const bf16x8*)&pbuf[w][kk * 512 + l * 8];
                for (int dt = 0; dt < 8; dt++) {
                    bf16x8 vf = *(const bf16x8*)&vtc[(dt * 2 + kk) * 512 + l * 8];
                    o[dt] = __builtin_amdgcn_mfma_f32_16x16x32_bf16(pf, vf, o[dt], 0, 0, 0);
                }
            }
            cur ^= 1;
        }

        // epilogue: O C-layout row q = quad*4+r, col d = lane16; l_s owned by lane16=q
        float inv[4];
        for (int r = 0; r < 4; r++) inv[r] = 1.0f / __shfl(l_s, (quad << 2) | r, 16);
        for (int r = 0; r < 4; r++) {
            const int qg = q0 + quad * 4 + r;
            bf16_t* dst = ctx + ((size_t)(b * SEQ + qg)) * (NH * HD) + h * HD;
            for (int dt = 0; dt < 8; dt++)
                dst[dt * 16 + lane16] = (bf16_t)(o[dt][r] * inv[r]);
        }
        __syncthreads();   // half boundary: protect LDS reuse
    }
}

// ---------------------------------------------------------------- launch
extern "C" void kernel_launch(void* const* d_in, const int* in_sizes, int n_in,
                              void* d_out, int out_size, void* d_ws, size_t ws_size,
                              hipStream_t stream) {
    const float* x  = (const float*)d_in[0];
    const int* pos  = (const int*)d_in[1];
    const float* Wq = (const float*)d_in[2];
    const float* Wk = (const float*)d_in[3];
    const float* Wv = (const float*)d_in[4];
    const float* Wo = (const float*)d_in[5];

    char* ws = (char*)d_ws;
    bf16_t* xb   = (bf16_t*)(ws);
    bf16_t* wqkv = (bf16_t*)(ws + (16u << 20));   // [6144,2048]
    bf16_t* wob  = (bf16_t*)(ws + (40u << 20));
    bf16_t* Qb   = (bf16_t*)(ws + (48u << 20));
    bf16_t* Kb   = (bf16_t*)(ws + (64u << 20));
    bf16_t* Vt   = (bf16_t*)(ws + (80u << 20));
    bf16_t* ctx  = (bf16_t*)(ws + (96u << 20));

    cast_f32_bf16<<<8192, 256, 0, stream>>>(x, xb, 2097152);
    cast_w4<<<16384, 256, 0, stream>>>(Wq, Wk, Wv, Wo, wqkv, wob);

    dim3 gq(6144 / 128, MM / 128);
    gemm_bt<3><<<gq, 256, 0, stream>>>(xb, wqkv, (void*)Qb, Kb, Vt);

    rope_kernel<<<16384, 256, 0, stream>>>(Qb, Kb, pos);

    attn_kernel<<<512, 256, 0, stream>>>(Qb, Kb, Vt, ctx);

    dim3 gg(2048 / 128, MM / 128);
    gemm_bt<1><<<gg, 256, 0, stream>>>(ctx, wob, d_out, nullptr, nullptr);
}

// Round 4
// 471.081 us; speedup vs baseline: 1.4752x; 1.0188x over previous
//
#include <hip/hip_runtime.h>
#include <cstdint>
#include <cstddef>

typedef __bf16 bf16_t;
typedef __bf16 bf16x8 __attribute__((ext_vector_type(8)));
typedef float  f32x4  __attribute__((ext_vector_type(4)));

#define SEQ 2048
#define NH  16
#define HD  128
#define MM  4096   // b*s rows
#define KK  2048

// async global->LDS, 16B per lane, LDS dest = wave-uniform base + lane*16
#define ASYNC16(g, l) __builtin_amdgcn_global_load_lds( \
    (const __attribute__((address_space(1))) void*)(g), \
    (__attribute__((address_space(3))) void*)(l), 16, 0, 0)

// ---------------------------------------------------------------- one cast kernel: x, Wq|Wk|Wv -> wqkv, Wo -> wob
__global__ __launch_bounds__(256) void cast_all(const float* __restrict__ x,
                                                const float* __restrict__ Wq,
                                                const float* __restrict__ Wk,
                                                const float* __restrict__ Wv,
                                                const float* __restrict__ Wo,
                                                bf16_t* __restrict__ xb,
                                                bf16_t* __restrict__ wqkv,
                                                bf16_t* __restrict__ wob) {
    int i = blockIdx.x * 256 + threadIdx.x;     // 0..6M-1 float4 groups
    const float* src;
    bf16_t* dst;
    int off;
    if (i < 2097152) { src = x; dst = xb; off = i; }
    else {
        int j = i - 2097152;
        int sel = j >> 20; off = j & 0xFFFFF;
        if (sel < 3) { src = (sel == 0) ? Wq : (sel == 1) ? Wk : Wv; dst = wqkv + (size_t)sel * 4194304; }
        else         { src = Wo; dst = wob; }
    }
    float4 v = ((const float4*)src)[off];
    union { bf16_t h[4]; uint2 u; } t;
    t.h[0] = (bf16_t)v.x; t.h[1] = (bf16_t)v.y;
    t.h[2] = (bf16_t)v.z; t.h[3] = (bf16_t)v.w;
    ((uint2*)dst)[off] = t.u;
}

// ---------------------------------------------------------------- GEMM  C = A * B^T
// A: [MM,KK] bf16 row-major; B: [N,KK] bf16 row-major (weights are [out,in]).
// MODE 3: fused QKV (N=6144): n<2048 -> Q (rope+scale) [b,h,s,d]; <4096 -> K (rope) [b,h,s,d];
//         else V^T [b,h,d,s].  All via LDS-transpose epilogue -> coalesced 16B stores.
// MODE 1: fp32 out row-major [MM,2048] (direct dword stores, already line-efficient)
template<int MODE>
__global__ __launch_bounds__(256) void gemm_bt(const bf16_t* __restrict__ A,
                                               const bf16_t* __restrict__ B,
                                               void* __restrict__ Cout,
                                               bf16_t* __restrict__ Kout,
                                               bf16_t* __restrict__ Vout,
                                               const int* __restrict__ pos) {
    // staging (16 KB) and epilogue transpose buffer (17 KB) share LDS
    __shared__ union SMem {
        struct { bf16_t A[8 * 512]; bf16_t B[8 * 512]; } st;
        bf16_t epi[64 * 136];                   // 64 rows x (128 + 8 pad)
    } sm;

    const int tid = threadIdx.x;
    const int w = tid >> 6, l = tid & 63;
    const int lane16 = l & 15, quad = l >> 4;
    const int tm = blockIdx.y, tn = blockIdx.x;
    const int wm = w >> 1, wn = w & 1;

    const bf16_t* pA0 = A + (size_t)(tm * 128 + (2 * w + 0) * 16 + lane16) * KK + quad * 8;
    const bf16_t* pA1 = A + (size_t)(tm * 128 + (2 * w + 1) * 16 + lane16) * KK + quad * 8;
    const bf16_t* pB0 = B + (size_t)(tn * 128 + (2 * w + 0) * 16 + lane16) * KK + quad * 8;
    const bf16_t* pB1 = B + (size_t)(tn * 128 + (2 * w + 1) * 16 + lane16) * KK + quad * 8;

    bf16_t* wA0 = &sm.st.A[(2 * w + 0) * 512];  // wave-uniform LDS bases
    bf16_t* wA1 = &sm.st.A[(2 * w + 1) * 512];
    bf16_t* wB0 = &sm.st.B[(2 * w + 0) * 512];
    bf16_t* wB1 = &sm.st.B[(2 * w + 1) * 512];
    const bf16_t* rA = &sm.st.A[wm * 4 * 512 + l * 8];
    const bf16_t* rB = &sm.st.B[wn * 4 * 512 + l * 8];

    f32x4 acc[4][4];
    for (int i = 0; i < 4; i++)
        for (int j = 0; j < 4; j++) acc[i][j] = (f32x4){0.f, 0.f, 0.f, 0.f};

    for (int k0 = 0; k0 < KK; k0 += 32) {
        __syncthreads();
        ASYNC16(pA0, wA0); ASYNC16(pA1, wA1);
        ASYNC16(pB0, wB0); ASYNC16(pB1, wB1);
        pA0 += 32; pA1 += 32; pB0 += 32; pB1 += 32;
        __syncthreads();
        bf16x8 af[4], bfr[4];
        for (int i = 0; i < 4; i++) af[i]  = *(const bf16x8*)(rA + i * 512);
        for (int j = 0; j < 4; j++) bfr[j] = *(const bf16x8*)(rB + j * 512);
        for (int i = 0; i < 4; i++)
            for (int j = 0; j < 4; j++)
                acc[i][j] = __builtin_amdgcn_mfma_f32_16x16x32_bf16(af[i], bfr[j], acc[i][j], 0, 0, 0);
    }

    if (MODE == 1) {
        // direct fp32 row-major stores: 4 rows x 64B full lines per inst
        const int mbase = tm * 128 + wm * 64;
        const int nbase = tn * 128 + wn * 64;
        for (int i = 0; i < 4; i++)
            for (int j = 0; j < 4; j++) {
                const int n  = nbase + j * 16 + lane16;
                const int m0 = mbase + i * 16 + quad * 4;
                for (int r = 0; r < 4; r++)
                    ((float*)Cout)[(size_t)(m0 + r) * 2048 + n] = acc[i][j][r];
            }
        return;
    }

    // ------------- MODE 3 LDS-transpose epilogue -------------
    const int mbase = tm * 128;
    const int nb    = tn * 128;
    const int sel   = nb >> 11;                 // 0=Q 1=K 2=V (uniform per block)
    const int hh    = (nb & 2047) >> 7;         // head (block covers exactly one head)
    const int bidx  = mbase >> 11;              // batch (tile within one b)
    const int g  = tid >> 4;                    // row-group for read-back
    const int c8 = (tid & 15) * 8;              // 8 contiguous cols per thread

    if (sel < 2) {
        // Q/K: out [b,h,s,d]; rope fused in read-back (8 contiguous d = 4 pairs)
        bf16_t* dstbase = ((sel == 0) ? (bf16_t*)Cout : Kout) +
                          (size_t)(bidx * NH + hh) * SEQ * HD;
        const float qs = (sel == 0) ? 0.08838834764831845f : 1.0f;  // 1/sqrt(128) on Q
        for (int half = 0; half < 2; half++) {
            __syncthreads();
            if (wm == half) {                   // 2 waves own this m-half
                for (int i = 0; i < 4; i++)
                    for (int j = 0; j < 4; j++)
                        for (int r = 0; r < 4; r++)
                            sm.epi[(i * 16 + quad * 4 + r) * 136 + wn * 64 + j * 16 + lane16] =
                                (bf16_t)acc[i][j][r];
            }
            __syncthreads();
            for (int p = 0; p < 4; p++) {
                const int rid = p * 16 + g;     // 0..63
                const int s = (mbase & 2047) + half * 64 + rid;
                bf16x8 v = *(const bf16x8*)&sm.epi[rid * 136 + c8];
                const float pp = (float)pos[bidx * SEQ + s];
                union { bf16_t h8[8]; uint4 u; } o;
                for (int t = 0; t < 4; t++) {
                    const int fi = (c8 >> 1) + t;                   // pair index 0..63
                    const float freq = exp2f(-(float)fi * 0.20762050593045857f);
                    const float ang = pp * freq;
                    const float sn = __sinf(ang), cs = __cosf(ang);
                    const float x1 = (float)v[2 * t], x2 = (float)v[2 * t + 1];
                    o.h8[2 * t]     = (bf16_t)((x1 * cs - x2 * sn) * qs);
                    o.h8[2 * t + 1] = (bf16_t)((x1 * sn + x2 * cs) * qs);
                }
                *(uint4*)(dstbase + (size_t)s * HD + c8) = o.u;
            }
        }
    } else {
        // V^T: out [b,h,d,s]; epi holds [d_local 64][m 128] per half
        bf16_t* dstb = Vout + (size_t)(bidx * NH + hh) * HD * SEQ;
        const int s0 = mbase & 2047;
        for (int half = 0; half < 2; half++) {
            __syncthreads();
            if (wn == half) {                   // 2 waves own this n-half
                for (int i = 0; i < 4; i++)
                    for (int j = 0; j < 4; j++) {
                        union { bf16_t h4[4]; uint2 u; } pk;
                        for (int r = 0; r < 4; r++) pk.h4[r] = (bf16_t)acc[i][j][r];
                        *(uint2*)&sm.epi[(j * 16 + lane16) * 136 + wm * 64 + i * 16 + quad * 4] = pk.u;
                    }
            }
            __syncthreads();
            for (int p = 0; p < 4; p++) {
                const int rid = p * 16 + g;     // d_local 0..63
                const int d = half * 64 + rid;
                bf16x8 v = *(const bf16x8*)&sm.epi[rid * 136 + c8];
                *(uint4*)(dstb + (size_t)d * SEQ + s0 + c8) = *(const uint4*)&v;
            }
        }
    }
}

// ---------------------------------------------------------------- causal flash attention
// Q,K: [b,h,s,d] bf16 (rope applied, Q pre-scaled).  Vt: [b,h,d,s] bf16.  ctx: [b,s,h*d] bf16.
// Block = 4 waves x 16 q-rows = 64-row q-tile; block processes q-tiles {bt, 31-bt}
// (perfect causal balance: 33 key-tile iterations per block).
// Grid flat 512: bh = idx&31 (fastest) so each XCD keeps ~4 (b,h) K/V sets in its L2.
// S^T = K*Q^T so each lane owns one q-row (cheap softmax); K/V double-buffered,
// one barrier per iteration, loads for kb+1 in flight during compute on kb.
__global__ __launch_bounds__(256) void attn_kernel(const bf16_t* __restrict__ Q,
                                                   const bf16_t* __restrict__ K,
                                                   const bf16_t* __restrict__ Vt,
                                                   bf16_t* __restrict__ ctx) {
    const int flat = blockIdx.x;
    const int bh = flat & 31;
    const int bt = flat >> 5;                   // 0..15
    const int h = bh & 15, b = bh >> 4;
    const bf16_t* Qh = Q  + (size_t)bh * SEQ * HD;
    const bf16_t* Kh = K  + (size_t)bh * SEQ * HD;
    const bf16_t* Vh = Vt + (size_t)bh * HD * SEQ;

    const int tid = threadIdx.x;
    const int w = tid >> 6, l = tid & 63;
    const int lane16 = l & 15, quad = l >> 4;

    // K tile (64 keys x 128 d): frag f=nt*4+kc: slot l=(key nt*16+(l&15), d kc*32+(l>>4)*8)
    __shared__ bf16_t kt[2][16 * 512];
    // V^T tile (128 d x 64 keys): frag f=dt*2+kk: slot l=(d dt*16+(l&15), key kk*32+(l>>4)*8)
    __shared__ bf16_t vt[2][16 * 512];
    // per-wave P^T->A-operand buffer (16 q x 64 k), 2 frags
    __shared__ bf16_t pbuf[4][1024];

    for (int half = 0; half < 2; half++) {
        const int qt = half ? (31 - bt) : bt;   // q-tile of 64 rows
        const int q0 = qt * 64 + w * 16;

        // Q fragments: lane holds Q[q0+lane16][kc*32+quad*8 ..+8] (A- and B-operand layout)
        bf16x8 qf[4];
        {
            const bf16_t* qrow = Qh + (size_t)(q0 + lane16) * HD + quad * 8;
            for (int kc = 0; kc < 4; kc++) qf[kc] = *(const bf16x8*)(qrow + kc * 32);
        }

        f32x4 o[8];
        for (int dt = 0; dt < 8; dt++) o[dt] = (f32x4){0.f, 0.f, 0.f, 0.f};
        float m_s = -INFINITY, l_s = 0.f;       // per-lane: row q = q0 + lane16

        // prologue: stage kb=0 into buffer 0
        __syncthreads();                        // protect LDS from previous half's reads
        for (int ii = 0; ii < 4; ii++) {
            const int f = w * 4 + ii;
            const int nt = f >> 2, kc = f & 3;
            ASYNC16(Kh + (size_t)(nt * 16 + lane16) * HD + kc * 32 + quad * 8, &kt[0][f * 512]);
            const int dt = f >> 1, kk = f & 1;
            ASYNC16(Vh + (size_t)(dt * 16 + lane16) * SEQ + kk * 32 + quad * 8, &vt[0][f * 512]);
        }

        int cur = 0;
        for (int kb = 0; kb <= qt; kb++) {
            const int k0 = kb * 64;
            __syncthreads();                    // drains cur's loads (issued 1 iter ago)
            if (kb < qt) {                      // prefetch next tile into other buffer
                const int kn = k0 + 64;
                for (int ii = 0; ii < 4; ii++) {
                    const int f = w * 4 + ii;
                    const int nt = f >> 2, kc = f & 3;
                    ASYNC16(Kh + (size_t)(kn + nt * 16 + lane16) * HD + kc * 32 + quad * 8,
                            &kt[1 - cur][f * 512]);
                    const int dt = f >> 1, kk = f & 1;
                    ASYNC16(Vh + (size_t)(dt * 16 + lane16) * SEQ + kn + kk * 32 + quad * 8,
                            &vt[1 - cur][f * 512]);
                }
            }
            const bf16_t* ktc = kt[cur];
            const bf16_t* vtc = vt[cur];

            // S^T = K Q^T : row = key-in-tile (quad*4+r), col = q (lane16)
            f32x4 sacc[4];
            for (int nt = 0; nt < 4; nt++) sacc[nt] = (f32x4){0.f, 0.f, 0.f, 0.f};
            for (int nt = 0; nt < 4; nt++)
                for (int kc = 0; kc < 4; kc++) {
                    bf16x8 kf = *(const bf16x8*)&ktc[(nt * 4 + kc) * 512 + l * 8];
                    sacc[nt] = __builtin_amdgcn_mfma_f32_16x16x32_bf16(kf, qf[kc], sacc[nt], 0, 0, 0);
                }
            if (kb == qt) {   // diagonal tile mask: key_g > q_g -> -inf
                const int qg = q0 + lane16;
                for (int nt = 0; nt < 4; nt++)
                    for (int r = 0; r < 4; r++) {
                        const int kg = k0 + nt * 16 + quad * 4 + r;
                        if (kg > qg) sacc[nt][r] = -INFINITY;
                    }
            }
            // per-lane softmax for row q = q0 + lane16
            float rowmax = sacc[0][0];
            for (int nt = 0; nt < 4; nt++)
                for (int r = 0; r < 4; r++) rowmax = fmaxf(rowmax, sacc[nt][r]);
            rowmax = fmaxf(rowmax, __shfl_xor(rowmax, 16, 64));
            rowmax = fmaxf(rowmax, __shfl_xor(rowmax, 32, 64));
            const float mnew = fmaxf(m_s, rowmax);
            const float a = __expf(m_s - mnew);
            m_s = mnew;
            float ssum = 0.f;
            for (int nt = 0; nt < 4; nt++) {
                union { bf16_t h4[4]; uint2 u; } pk;
                for (int r = 0; r < 4; r++) {
                    const float e = __expf(sacc[nt][r] - mnew);   // exp(-inf)=0
                    ssum += e;
                    pk.h4[r] = (bf16_t)e;
                }
                // A-operand-native slot for (q=lane16, key=nt*16+quad*4+r)
                const int addr = (nt >> 1) * 512 +
                                 (((nt & 1) * 2 + (quad >> 1)) * 16 + lane16) * 8 +
                                 (quad & 1) * 4;
                *(uint2*)&pbuf[w][addr] = pk.u;
            }
            ssum += __shfl_xor(ssum, 16, 64);
            ssum += __shfl_xor(ssum, 32, 64);
            l_s = l_s * a + ssum;

            // redistribute alpha to O rows (O row q = quad*4+r), rescale, then O += P V
            float ar[4];
            for (int r = 0; r < 4; r++) ar[r] = __shfl(a, (quad << 2) | r, 16);
            for (int dt = 0; dt < 8; dt++)
                for (int r = 0; r < 4; r++) o[dt][r] *= ar[r];
            for (int kk = 0; kk < 2; kk++) {
                bf16x8 pf = *(const bf16x8*)&pbuf[w][kk * 512 + l * 8];
                for (int dt = 0; dt < 8; dt++) {
                    bf16x8 vf = *(const bf16x8*)&vtc[(dt * 2 + kk) * 512 + l * 8];
                    o[dt] = __builtin_amdgcn_mfma_f32_16x16x32_bf16(pf, vf, o[dt], 0, 0, 0);
                }
            }
            cur ^= 1;
        }

        // epilogue: O C-layout row q = quad*4+r, col d = lane16; l_s owned by lane16=q
        float inv[4];
        for (int r = 0; r < 4; r++) inv[r] = 1.0f / __shfl(l_s, (quad << 2) | r, 16);
        for (int r = 0; r < 4; r++) {
            const int qg = q0 + quad * 4 + r;
            bf16_t* dst = ctx + ((size_t)(b * SEQ + qg)) * (NH * HD) + h * HD;
            for (int dt = 0; dt < 8; dt++)
                dst[dt * 16 + lane16] = (bf16_t)(o[dt][r] * inv[r]);
        }
        __syncthreads();   // half boundary: protect LDS reuse
    }
}

// ---------------------------------------------------------------- launch
extern "C" void kernel_launch(void* const* d_in, const int* in_sizes, int n_in,
                              void* d_out, int out_size, void* d_ws, size_t ws_size,
                              hipStream_t stream) {
    const float* x  = (const float*)d_in[0];
    const int* pos  = (const int*)d_in[1];
    const float* Wq = (const float*)d_in[2];
    const float* Wk = (const float*)d_in[3];
    const float* Wv = (const float*)d_in[4];
    const float* Wo = (const float*)d_in[5];

    char* ws = (char*)d_ws;
    bf16_t* xb   = (bf16_t*)(ws);
    bf16_t* wqkv = (bf16_t*)(ws + (16u << 20));   // [6144,2048]
    bf16_t* wob  = (bf16_t*)(ws + (40u << 20));
    bf16_t* Qb   = (bf16_t*)(ws + (48u << 20));
    bf16_t* Kb   = (bf16_t*)(ws + (64u << 20));
    bf16_t* Vt   = (bf16_t*)(ws + (80u << 20));
    bf16_t* ctx  = (bf16_t*)(ws + (96u << 20));

    cast_all<<<24576, 256, 0, stream>>>(x, Wq, Wk, Wv, Wo, xb, wqkv, wob);

    dim3 gq(6144 / 128, MM / 128);
    gemm_bt<3><<<gq, 256, 0, stream>>>(xb, wqkv, (void*)Qb, Kb, Vt, pos);

    attn_kernel<<<512, 256, 0, stream>>>(Qb, Kb, Vt, ctx);

    dim3 gg(2048 / 128, MM / 128);
    gemm_bt<1><<<gg, 256, 0, stream>>>(ctx, wob, d_out, nullptr, nullptr, nullptr);
}

// Round 5
// 462.336 us; speedup vs baseline: 1.5031x; 1.0189x over previous
//
#include <hip/hip_runtime.h>
#include <cstdint>
#include <cstddef>

typedef __bf16 bf16_t;
typedef __bf16 bf16x8 __attribute__((ext_vector_type(8)));
typedef float  f32x4  __attribute__((ext_vector_type(4)));

#define SEQ 2048
#define NH  16
#define HD  128
#define MM  4096   // b*s rows
#define KK  2048

// async global->LDS, 16B per lane, LDS dest = wave-uniform base + lane*16
#define ASYNC16(g, l) __builtin_amdgcn_global_load_lds( \
    (const __attribute__((address_space(1))) void*)(g), \
    (__attribute__((address_space(3))) void*)(l), 16, 0, 0)

// ---------------------------------------------------------------- one cast kernel
__global__ __launch_bounds__(256) void cast_all(const float* __restrict__ x,
                                                const float* __restrict__ Wq,
                                                const float* __restrict__ Wk,
                                                const float* __restrict__ Wv,
                                                const float* __restrict__ Wo,
                                                bf16_t* __restrict__ xb,
                                                bf16_t* __restrict__ wqkv,
                                                bf16_t* __restrict__ wob) {
    int i = blockIdx.x * 256 + threadIdx.x;     // 0..6M-1 float4 groups
    const float* src;
    bf16_t* dst;
    int off;
    if (i < 2097152) { src = x; dst = xb; off = i; }
    else {
        int j = i - 2097152;
        int sel = j >> 20; off = j & 0xFFFFF;
        if (sel < 3) { src = (sel == 0) ? Wq : (sel == 1) ? Wk : Wv; dst = wqkv + (size_t)sel * 4194304; }
        else         { src = Wo; dst = wob; }
    }
    float4 v = ((const float4*)src)[off];
    union { bf16_t h[4]; uint2 u; } t;
    t.h[0] = (bf16_t)v.x; t.h[1] = (bf16_t)v.y;
    t.h[2] = (bf16_t)v.z; t.h[3] = (bf16_t)v.w;
    ((uint2*)dst)[off] = t.u;
}

// ---------------------------------------------------------------- GEMM core  C = A * B^T
// BK=64: one barrier pair per 64-k step -> 32 MFMA + 16 ds_read_b128 per wave per drain.
union SMemU {
    struct { bf16_t A[2][4096]; bf16_t B[2][4096]; } st;   // [k-half][frag f*512 + slot l*8]
    bf16_t epi[64 * 136];                                  // epilogue transpose (64 x 128+8pad)
};

template<int MODE>
__device__ __forceinline__ void gemm_body(SMemU& sm,
                                          const bf16_t* __restrict__ A,
                                          const bf16_t* __restrict__ B,
                                          void* __restrict__ Cout,
                                          bf16_t* __restrict__ Kout,
                                          bf16_t* __restrict__ Vout,
                                          const int* __restrict__ pos) {
    const int tid = threadIdx.x;
    const int w = tid >> 6, l = tid & 63;
    const int lane16 = l & 15, quad = l >> 4;
    const int tm = blockIdx.y, tn = blockIdx.x;
    const int wm = w >> 1, wn = w & 1;

    const bf16_t* pA0 = A + (size_t)(tm * 128 + (2 * w + 0) * 16 + lane16) * KK + quad * 8;
    const bf16_t* pA1 = A + (size_t)(tm * 128 + (2 * w + 1) * 16 + lane16) * KK + quad * 8;
    const bf16_t* pB0 = B + (size_t)(tn * 128 + (2 * w + 0) * 16 + lane16) * KK + quad * 8;
    const bf16_t* pB1 = B + (size_t)(tn * 128 + (2 * w + 1) * 16 + lane16) * KK + quad * 8;

    bf16_t* wA0_0 = &sm.st.A[0][(2 * w + 0) * 512];   // wave-uniform LDS bases
    bf16_t* wA1_0 = &sm.st.A[0][(2 * w + 1) * 512];
    bf16_t* wA0_1 = &sm.st.A[1][(2 * w + 0) * 512];
    bf16_t* wA1_1 = &sm.st.A[1][(2 * w + 1) * 512];
    bf16_t* wB0_0 = &sm.st.B[0][(2 * w + 0) * 512];
    bf16_t* wB1_0 = &sm.st.B[0][(2 * w + 1) * 512];
    bf16_t* wB0_1 = &sm.st.B[1][(2 * w + 0) * 512];
    bf16_t* wB1_1 = &sm.st.B[1][(2 * w + 1) * 512];

    f32x4 acc[4][4];
    for (int i = 0; i < 4; i++)
        for (int j = 0; j < 4; j++) acc[i][j] = (f32x4){0.f, 0.f, 0.f, 0.f};

    for (int k0 = 0; k0 < KK; k0 += 64) {
        __syncthreads();
        ASYNC16(pA0, wA0_0); ASYNC16(pA1, wA1_0);
        ASYNC16(pB0, wB0_0); ASYNC16(pB1, wB1_0);
        ASYNC16(pA0 + 32, wA0_1); ASYNC16(pA1 + 32, wA1_1);
        ASYNC16(pB0 + 32, wB0_1); ASYNC16(pB1 + 32, wB1_1);
        pA0 += 64; pA1 += 64; pB0 += 64; pB1 += 64;
        __syncthreads();
        #pragma unroll
        for (int kh = 0; kh < 2; kh++) {
            const bf16_t* rA = &sm.st.A[kh][wm * 2048 + l * 8];
            const bf16_t* rB = &sm.st.B[kh][wn * 2048 + l * 8];
            bf16x8 af[4], bfr[4];
            for (int i = 0; i < 4; i++) af[i]  = *(const bf16x8*)(rA + i * 512);
            for (int j = 0; j < 4; j++) bfr[j] = *(const bf16x8*)(rB + j * 512);
            for (int i = 0; i < 4; i++)
                for (int j = 0; j < 4; j++)
                    acc[i][j] = __builtin_amdgcn_mfma_f32_16x16x32_bf16(af[i], bfr[j], acc[i][j], 0, 0, 0);
        }
    }

    if (MODE == 1) {
        // direct fp32 row-major stores: 16 lanes x 4B = 64B full lines
        const int mbase = tm * 128 + wm * 64;
        const int nbase = tn * 128 + wn * 64;
        for (int i = 0; i < 4; i++)
            for (int j = 0; j < 4; j++) {
                const int n  = nbase + j * 16 + lane16;
                const int m0 = mbase + i * 16 + quad * 4;
                for (int r = 0; r < 4; r++)
                    ((float*)Cout)[(size_t)(m0 + r) * 2048 + n] = acc[i][j][r];
            }
        return;
    }

    // ------------- MODE 3 LDS-transpose epilogue (QKV + fused RoPE) -------------
    const int mbase = tm * 128;
    const int nb    = tn * 128;
    const int sel   = nb >> 11;                 // 0=Q 1=K 2=V (uniform per block)
    const int hh    = (nb & 2047) >> 7;         // head
    const int bidx  = mbase >> 11;              // batch
    const int g  = tid >> 4;
    const int c8 = (tid & 15) * 8;

    if (sel < 2) {
        bf16_t* dstbase = ((sel == 0) ? (bf16_t*)Cout : Kout) +
                          (size_t)(bidx * NH + hh) * SEQ * HD;
        const float qs = (sel == 0) ? 0.08838834764831845f : 1.0f;  // 1/sqrt(128) on Q
        for (int half = 0; half < 2; half++) {
            __syncthreads();
            if (wm == half) {
                for (int i = 0; i < 4; i++)
                    for (int j = 0; j < 4; j++)
                        for (int r = 0; r < 4; r++)
                            sm.epi[(i * 16 + quad * 4 + r) * 136 + wn * 64 + j * 16 + lane16] =
                                (bf16_t)acc[i][j][r];
            }
            __syncthreads();
            for (int p = 0; p < 4; p++) {
                const int rid = p * 16 + g;
                const int s = (mbase & 2047) + half * 64 + rid;
                bf16x8 v = *(const bf16x8*)&sm.epi[rid * 136 + c8];
                const float pp = (float)pos[bidx * SEQ + s];
                union { bf16_t h8[8]; uint4 u; } o;
                for (int t = 0; t < 4; t++) {
                    const int fi = (c8 >> 1) + t;
                    const float freq = exp2f(-(float)fi * 0.20762050593045857f);
                    const float ang = pp * freq;
                    const float sn = __sinf(ang), cs = __cosf(ang);
                    const float x1 = (float)v[2 * t], x2 = (float)v[2 * t + 1];
                    o.h8[2 * t]     = (bf16_t)((x1 * cs - x2 * sn) * qs);
                    o.h8[2 * t + 1] = (bf16_t)((x1 * sn + x2 * cs) * qs);
                }
                *(uint4*)(dstbase + (size_t)s * HD + c8) = o.u;
            }
        }
    } else {
        bf16_t* dstb = Vout + (size_t)(bidx * NH + hh) * HD * SEQ;
        const int s0 = mbase & 2047;
        for (int half = 0; half < 2; half++) {
            __syncthreads();
            if (wn == half) {
                for (int i = 0; i < 4; i++)
                    for (int j = 0; j < 4; j++) {
                        union { bf16_t h4[4]; uint2 u; } pk;
                        for (int r = 0; r < 4; r++) pk.h4[r] = (bf16_t)acc[i][j][r];
                        *(uint2*)&sm.epi[(j * 16 + lane16) * 136 + wm * 64 + i * 16 + quad * 4] = pk.u;
                    }
            }
            __syncthreads();
            for (int p = 0; p < 4; p++) {
                const int rid = p * 16 + g;
                const int d = half * 64 + rid;
                bf16x8 v = *(const bf16x8*)&sm.epi[rid * 136 + c8];
                *(uint4*)(dstb + (size_t)d * SEQ + s0 + c8) = *(const uint4*)&v;
            }
        }
    }
}

__global__ __launch_bounds__(256) void gemm_qkv(const bf16_t* __restrict__ A,
                                                const bf16_t* __restrict__ B,
                                                bf16_t* __restrict__ Qout,
                                                bf16_t* __restrict__ Kout,
                                                bf16_t* __restrict__ Vout,
                                                const int* __restrict__ pos) {
    __shared__ SMemU sm;
    gemm_body<3>(sm, A, B, (void*)Qout, Kout, Vout, pos);
}

__global__ __launch_bounds__(256) void gemm_out(const bf16_t* __restrict__ A,
                                                const bf16_t* __restrict__ B,
                                                float* __restrict__ Cout) {
    __shared__ SMemU sm;
    gemm_body<1>(sm, A, B, (void*)Cout, nullptr, nullptr, nullptr);
}

// ---------------------------------------------------------------- causal flash attention
// Q,K: [b,h,s,d] bf16 (rope applied, Q pre-scaled).  Vt: [b,h,d,s] bf16.  ctx: [b,s,h*d] bf16.
__global__ __launch_bounds__(256) void attn_kernel(const bf16_t* __restrict__ Q,
                                                   const bf16_t* __restrict__ K,
                                                   const bf16_t* __restrict__ Vt,
                                                   bf16_t* __restrict__ ctx) {
    const int flat = blockIdx.x;
    const int bh = flat & 31;
    const int bt = flat >> 5;                   // 0..15
    const int h = bh & 15, b = bh >> 4;
    const bf16_t* Qh = Q  + (size_t)bh * SEQ * HD;
    const bf16_t* Kh = K  + (size_t)bh * SEQ * HD;
    const bf16_t* Vh = Vt + (size_t)bh * HD * SEQ;

    const int tid = threadIdx.x;
    const int w = tid >> 6, l = tid & 63;
    const int lane16 = l & 15, quad = l >> 4;

    __shared__ bf16_t kt[2][16 * 512];
    __shared__ bf16_t vt[2][16 * 512];
    __shared__ bf16_t pbuf[4][1024];

    for (int half = 0; half < 2; half++) {
        const int qt = half ? (31 - bt) : bt;   // q-tile of 64 rows
        const int q0 = qt * 64 + w * 16;

        bf16x8 qf[4];
        {
            const bf16_t* qrow = Qh + (size_t)(q0 + lane16) * HD + quad * 8;
            for (int kc = 0; kc < 4; kc++) qf[kc] = *(const bf16x8*)(qrow + kc * 32);
        }

        f32x4 o[8];
        for (int dt = 0; dt < 8; dt++) o[dt] = (f32x4){0.f, 0.f, 0.f, 0.f};
        float m_s = -INFINITY, l_s = 0.f;       // per-lane: row q = q0 + lane16

        __syncthreads();
        for (int ii = 0; ii < 4; ii++) {
            const int f = w * 4 + ii;
            const int nt = f >> 2, kc = f & 3;
            ASYNC16(Kh + (size_t)(nt * 16 + lane16) * HD + kc * 32 + quad * 8, &kt[0][f * 512]);
            const int dt = f >> 1, kk = f & 1;
            ASYNC16(Vh + (size_t)(dt * 16 + lane16) * SEQ + kk * 32 + quad * 8, &vt[0][f * 512]);
        }

        int cur = 0;
        for (int kb = 0; kb <= qt; kb++) {
            const int k0 = kb * 64;
            __syncthreads();
            if (kb < qt) {
                const int kn = k0 + 64;
                for (int ii = 0; ii < 4; ii++) {
                    const int f = w * 4 + ii;
                    const int nt = f >> 2, kc = f & 3;
                    ASYNC16(Kh + (size_t)(kn + nt * 16 + lane16) * HD + kc * 32 + quad * 8,
                            &kt[1 - cur][f * 512]);
                    const int dt = f >> 1, kk = f & 1;
                    ASYNC16(Vh + (size_t)(dt * 16 + lane16) * SEQ + kn + kk * 32 + quad * 8,
                            &vt[1 - cur][f * 512]);
                }
            }
            const bf16_t* ktc = kt[cur];
            const bf16_t* vtc = vt[cur];

            f32x4 sacc[4];
            for (int nt = 0; nt < 4; nt++) sacc[nt] = (f32x4){0.f, 0.f, 0.f, 0.f};
            for (int nt = 0; nt < 4; nt++)
                for (int kc = 0; kc < 4; kc++) {
                    bf16x8 kf = *(const bf16x8*)&ktc[(nt * 4 + kc) * 512 + l * 8];
                    sacc[nt] = __builtin_amdgcn_mfma_f32_16x16x32_bf16(kf, qf[kc], sacc[nt], 0, 0, 0);
                }
            if (kb == qt) {
                const int qg = q0 + lane16;
                for (int nt = 0; nt < 4; nt++)
                    for (int r = 0; r < 4; r++) {
                        const int kg = k0 + nt * 16 + quad * 4 + r;
                        if (kg > qg) sacc[nt][r] = -INFINITY;
                    }
            }
            float rowmax = sacc[0][0];
            for (int nt = 0; nt < 4; nt++)
                for (int r = 0; r < 4; r++) rowmax = fmaxf(rowmax, sacc[nt][r]);
            rowmax = fmaxf(rowmax, __shfl_xor(rowmax, 16, 64));
            rowmax = fmaxf(rowmax, __shfl_xor(rowmax, 32, 64));
            const float mnew = fmaxf(m_s, rowmax);
            const float a = __expf(m_s - mnew);
            m_s = mnew;
            float ssum = 0.f;
            for (int nt = 0; nt < 4; nt++) {
                union { bf16_t h4[4]; uint2 u; } pk;
                for (int r = 0; r < 4; r++) {
                    const float e = __expf(sacc[nt][r] - mnew);
                    ssum += e;
                    pk.h4[r] = (bf16_t)e;
                }
                const int addr = (nt >> 1) * 512 +
                                 (((nt & 1) * 2 + (quad >> 1)) * 16 + lane16) * 8 +
                                 (quad & 1) * 4;
                *(uint2*)&pbuf[w][addr] = pk.u;
            }
            ssum += __shfl_xor(ssum, 16, 64);
            ssum += __shfl_xor(ssum, 32, 64);
            l_s = l_s * a + ssum;

            float ar[4];
            for (int r = 0; r < 4; r++) ar[r] = __shfl(a, (quad << 2) | r, 16);
            for (int dt = 0; dt < 8; dt++)
                for (int r = 0; r < 4; r++) o[dt][r] *= ar[r];
            for (int kk = 0; kk < 2; kk++) {
                bf16x8 pf = *(const bf16x8*)&pbuf[w][kk * 512 + l * 8];
                for (int dt = 0; dt < 8; dt++) {
                    bf16x8 vf = *(const bf16x8*)&vtc[(dt * 2 + kk) * 512 + l * 8];
                    o[dt] = __builtin_amdgcn_mfma_f32_16x16x32_bf16(pf, vf, o[dt], 0, 0, 0);
                }
            }
            cur ^= 1;
        }

        float inv[4];
        for (int r = 0; r < 4; r++) inv[r] = 1.0f / __shfl(l_s, (quad << 2) | r, 16);
        for (int r = 0; r < 4; r++) {
            const int qg = q0 + quad * 4 + r;
            bf16_t* dst = ctx + ((size_t)(b * SEQ + qg)) * (NH * HD) + h * HD;
            for (int dt = 0; dt < 8; dt++)
                dst[dt * 16 + lane16] = (bf16_t)(o[dt][r] * inv[r]);
        }
        __syncthreads();
    }
}

// ---------------------------------------------------------------- launch
extern "C" void kernel_launch(void* const* d_in, const int* in_sizes, int n_in,
                              void* d_out, int out_size, void* d_ws, size_t ws_size,
                              hipStream_t stream) {
    const float* x  = (const float*)d_in[0];
    const int* pos  = (const int*)d_in[1];
    const float* Wq = (const float*)d_in[2];
    const float* Wk = (const float*)d_in[3];
    const float* Wv = (const float*)d_in[4];
    const float* Wo = (const float*)d_in[5];

    char* ws = (char*)d_ws;
    bf16_t* xb   = (bf16_t*)(ws);
    bf16_t* wqkv = (bf16_t*)(ws + (16u << 20));   // [6144,2048]
    bf16_t* wob  = (bf16_t*)(ws + (40u << 20));
    bf16_t* Qb   = (bf16_t*)(ws + (48u << 20));
    bf16_t* Kb   = (bf16_t*)(ws + (64u << 20));
    bf16_t* Vt   = (bf16_t*)(ws + (80u << 20));
    bf16_t* ctx  = (bf16_t*)(ws + (96u << 20));

    cast_all<<<24576, 256, 0, stream>>>(x, Wq, Wk, Wv, Wo, xb, wqkv, wob);

    dim3 gq(6144 / 128, MM / 128);
    gemm_qkv<<<gq, 256, 0, stream>>>(xb, wqkv, Qb, Kb, Vt, pos);

    attn_kernel<<<512, 256, 0, stream>>>(Qb, Kb, Vt, ctx);

    dim3 gg(2048 / 128, MM / 128);
    gemm_out<<<gg, 256, 0, stream>>>(ctx, wob, (float*)d_out);
}

// Round 6
// 460.577 us; speedup vs baseline: 1.5088x; 1.0038x over previous
//
#include <hip/hip_runtime.h>
#include <cstdint>
#include <cstddef>

typedef __bf16 bf16_t;
typedef __bf16 bf16x8 __attribute__((ext_vector_type(8)));
typedef float  f32x4  __attribute__((ext_vector_type(4)));

#define SEQ 2048
#define NH  16
#define HD  128
#define MM  4096   // b*s rows
#define KK  2048

// async global->LDS, 16B per lane, LDS dest = wave-uniform base + lane*16
#define ASYNC16(g, l) __builtin_amdgcn_global_load_lds( \
    (const __attribute__((address_space(1))) void*)(g), \
    (__attribute__((address_space(3))) void*)(l), 16, 0, 0)

// ---------------------------------------------------------------- one cast kernel
__global__ __launch_bounds__(256) void cast_all(const float* __restrict__ x,
                                                const float* __restrict__ Wq,
                                                const float* __restrict__ Wk,
                                                const float* __restrict__ Wv,
                                                const float* __restrict__ Wo,
                                                bf16_t* __restrict__ xb,
                                                bf16_t* __restrict__ wqkv,
                                                bf16_t* __restrict__ wob) {
    int i = blockIdx.x * 256 + threadIdx.x;     // 0..6M-1 float4 groups
    const float* src;
    bf16_t* dst;
    int off;
    if (i < 2097152) { src = x; dst = xb; off = i; }
    else {
        int j = i - 2097152;
        int sel = j >> 20; off = j & 0xFFFFF;
        if (sel < 3) { src = (sel == 0) ? Wq : (sel == 1) ? Wk : Wv; dst = wqkv + (size_t)sel * 4194304; }
        else         { src = Wo; dst = wob; }
    }
    float4 v = ((const float4*)src)[off];
    union { bf16_t h[4]; uint2 u; } t;
    t.h[0] = (bf16_t)v.x; t.h[1] = (bf16_t)v.y;
    t.h[2] = (bf16_t)v.z; t.h[3] = (bf16_t)v.w;
    ((uint2*)dst)[off] = t.u;
}

// ---------------------------------------------------------------- GEMM core  C = A * B^T
// BK=32, double-buffered staging: loads for tile k+1 are issued right after the
// barrier that drains tile k's loads, so each load has a full compute phase
// (x co-resident waves) in flight before anything waits on it.
union SMemU {
    struct { bf16_t A[2][4096]; bf16_t B[2][4096]; } st;   // [buf][frag f*512 + slot l*8]
    bf16_t epi[64 * 136];                                  // epilogue transpose (64 x 128+8pad)
};

template<int MODE>
__device__ __forceinline__ void gemm_body(SMemU& sm,
                                          const bf16_t* __restrict__ A,
                                          const bf16_t* __restrict__ B,
                                          void* __restrict__ Cout,
                                          bf16_t* __restrict__ Kout,
                                          bf16_t* __restrict__ Vout,
                                          const int* __restrict__ pos) {
    const int tid = threadIdx.x;
    const int w = tid >> 6, l = tid & 63;
    const int lane16 = l & 15, quad = l >> 4;
    const int tm = blockIdx.y, tn = blockIdx.x;
    const int wm = w >> 1, wn = w & 1;

    const bf16_t* pA0 = A + (size_t)(tm * 128 + (2 * w + 0) * 16 + lane16) * KK + quad * 8;
    const bf16_t* pA1 = A + (size_t)(tm * 128 + (2 * w + 1) * 16 + lane16) * KK + quad * 8;
    const bf16_t* pB0 = B + (size_t)(tn * 128 + (2 * w + 0) * 16 + lane16) * KK + quad * 8;
    const bf16_t* pB1 = B + (size_t)(tn * 128 + (2 * w + 1) * 16 + lane16) * KK + quad * 8;

    f32x4 acc[4][4];
    for (int i = 0; i < 4; i++)
        for (int j = 0; j < 4; j++) acc[i][j] = (f32x4){0.f, 0.f, 0.f, 0.f};

    // prologue: stage tile 0 into buffer 0
    ASYNC16(pA0, &sm.st.A[0][(2 * w + 0) * 512]);
    ASYNC16(pA1, &sm.st.A[0][(2 * w + 1) * 512]);
    ASYNC16(pB0, &sm.st.B[0][(2 * w + 0) * 512]);
    ASYNC16(pB1, &sm.st.B[0][(2 * w + 1) * 512]);

    int cur = 0;
    for (int k0 = 0; k0 < KK; k0 += 32) {
        __syncthreads();                        // drains tile-k loads (issued 1 iter ago)
        if (k0 + 32 < KK) {                     // prefetch tile k+1 into other buffer
            const int nbuf = 1 - cur;
            ASYNC16(pA0 + 32, &sm.st.A[nbuf][(2 * w + 0) * 512]);
            ASYNC16(pA1 + 32, &sm.st.A[nbuf][(2 * w + 1) * 512]);
            ASYNC16(pB0 + 32, &sm.st.B[nbuf][(2 * w + 0) * 512]);
            ASYNC16(pB1 + 32, &sm.st.B[nbuf][(2 * w + 1) * 512]);
            pA0 += 32; pA1 += 32; pB0 += 32; pB1 += 32;
        }
        const bf16_t* rA = &sm.st.A[cur][wm * 2048 + l * 8];
        const bf16_t* rB = &sm.st.B[cur][wn * 2048 + l * 8];
        bf16x8 af[4], bfr[4];
        for (int i = 0; i < 4; i++) af[i]  = *(const bf16x8*)(rA + i * 512);
        for (int j = 0; j < 4; j++) bfr[j] = *(const bf16x8*)(rB + j * 512);
        for (int i = 0; i < 4; i++)
            for (int j = 0; j < 4; j++)
                acc[i][j] = __builtin_amdgcn_mfma_f32_16x16x32_bf16(af[i], bfr[j], acc[i][j], 0, 0, 0);
        cur ^= 1;
    }

    if (MODE == 1) {
        // direct fp32 row-major stores: 16 lanes x 4B = 64B full lines
        const int mbase = tm * 128 + wm * 64;
        const int nbase = tn * 128 + wn * 64;
        for (int i = 0; i < 4; i++)
            for (int j = 0; j < 4; j++) {
                const int n  = nbase + j * 16 + lane16;
                const int m0 = mbase + i * 16 + quad * 4;
                for (int r = 0; r < 4; r++)
                    ((float*)Cout)[(size_t)(m0 + r) * 2048 + n] = acc[i][j][r];
            }
        return;
    }

    // ------------- MODE 3 LDS-transpose epilogue (QKV + fused RoPE) -------------
    const int mbase = tm * 128;
    const int nb    = tn * 128;
    const int sel   = nb >> 11;                 // 0=Q 1=K 2=V (uniform per block)
    const int hh    = (nb & 2047) >> 7;         // head
    const int bidx  = mbase >> 11;              // batch
    const int g  = tid >> 4;
    const int c8 = (tid & 15) * 8;

    if (sel < 2) {
        bf16_t* dstbase = ((sel == 0) ? (bf16_t*)Cout : Kout) +
                          (size_t)(bidx * NH + hh) * SEQ * HD;
        const float qs = (sel == 0) ? 0.08838834764831845f : 1.0f;  // 1/sqrt(128) on Q
        for (int half = 0; half < 2; half++) {
            __syncthreads();
            if (wm == half) {
                for (int i = 0; i < 4; i++)
                    for (int j = 0; j < 4; j++)
                        for (int r = 0; r < 4; r++)
                            sm.epi[(i * 16 + quad * 4 + r) * 136 + wn * 64 + j * 16 + lane16] =
                                (bf16_t)acc[i][j][r];
            }
            __syncthreads();
            for (int p = 0; p < 4; p++) {
                const int rid = p * 16 + g;
                const int s = (mbase & 2047) + half * 64 + rid;
                bf16x8 v = *(const bf16x8*)&sm.epi[rid * 136 + c8];
                const float pp = (float)pos[bidx * SEQ + s];
                union { bf16_t h8[8]; uint4 u; } o;
                for (int t = 0; t < 4; t++) {
                    const int fi = (c8 >> 1) + t;
                    const float freq = exp2f(-(float)fi * 0.20762050593045857f);
                    const float ang = pp * freq;
                    const float sn = __sinf(ang), cs = __cosf(ang);
                    const float x1 = (float)v[2 * t], x2 = (float)v[2 * t + 1];
                    o.h8[2 * t]     = (bf16_t)((x1 * cs - x2 * sn) * qs);
                    o.h8[2 * t + 1] = (bf16_t)((x1 * sn + x2 * cs) * qs);
                }
                *(uint4*)(dstbase + (size_t)s * HD + c8) = o.u;
            }
        }
    } else {
        bf16_t* dstb = Vout + (size_t)(bidx * NH + hh) * HD * SEQ;
        const int s0 = mbase & 2047;
        for (int half = 0; half < 2; half++) {
            __syncthreads();
            if (wn == half) {
                for (int i = 0; i < 4; i++)
                    for (int j = 0; j < 4; j++) {
                        union { bf16_t h4[4]; uint2 u; } pk;
                        for (int r = 0; r < 4; r++) pk.h4[r] = (bf16_t)acc[i][j][r];
                        *(uint2*)&sm.epi[(j * 16 + lane16) * 136 + wm * 64 + i * 16 + quad * 4] = pk.u;
                    }
            }
            __syncthreads();
            for (int p = 0; p < 4; p++) {
                const int rid = p * 16 + g;
                const int d = half * 64 + rid;
                bf16x8 v = *(const bf16x8*)&sm.epi[rid * 136 + c8];
                *(uint4*)(dstb + (size_t)d * SEQ + s0 + c8) = *(const uint4*)&v;
            }
        }
    }
}

__global__ __launch_bounds__(256) void gemm_qkv(const bf16_t* __restrict__ A,
                                                const bf16_t* __restrict__ B,
                                                bf16_t* __restrict__ Qout,
                                                bf16_t* __restrict__ Kout,
                                                bf16_t* __restrict__ Vout,
                                                const int* __restrict__ pos) {
    __shared__ SMemU sm;
    gemm_body<3>(sm, A, B, (void*)Qout, Kout, Vout, pos);
}

__global__ __launch_bounds__(256) void gemm_out(const bf16_t* __restrict__ A,
                                                const bf16_t* __restrict__ B,
                                                float* __restrict__ Cout) {
    __shared__ SMemU sm;
    gemm_body<1>(sm, A, B, (void*)Cout, nullptr, nullptr, nullptr);
}

// ---------------------------------------------------------------- causal flash attention
// Q,K: [b,h,s,d] bf16 (rope applied, Q pre-scaled).  Vt: [b,h,d,s] bf16.  ctx: [b,s,h*d] bf16.
__global__ __launch_bounds__(256) void attn_kernel(const bf16_t* __restrict__ Q,
                                                   const bf16_t* __restrict__ K,
                                                   const bf16_t* __restrict__ Vt,
                                                   bf16_t* __restrict__ ctx) {
    const int flat = blockIdx.x;
    const int bh = flat & 31;
    const int bt = flat >> 5;                   // 0..15
    const int h = bh & 15, b = bh >> 4;
    const bf16_t* Qh = Q  + (size_t)bh * SEQ * HD;
    const bf16_t* Kh = K  + (size_t)bh * SEQ * HD;
    const bf16_t* Vh = Vt + (size_t)bh * HD * SEQ;

    const int tid = threadIdx.x;
    const int w = tid >> 6, l = tid & 63;
    const int lane16 = l & 15, quad = l >> 4;

    __shared__ bf16_t kt[2][16 * 512];
    __shared__ bf16_t vt[2][16 * 512];
    __shared__ bf16_t pbuf[4][1024];

    for (int half = 0; half < 2; half++) {
        const int qt = half ? (31 - bt) : bt;   // q-tile of 64 rows
        const int q0 = qt * 64 + w * 16;

        bf16x8 qf[4];
        {
            const bf16_t* qrow = Qh + (size_t)(q0 + lane16) * HD + quad * 8;
            for (int kc = 0; kc < 4; kc++) qf[kc] = *(const bf16x8*)(qrow + kc * 32);
        }

        f32x4 o[8];
        for (int dt = 0; dt < 8; dt++) o[dt] = (f32x4){0.f, 0.f, 0.f, 0.f};
        float m_s = -INFINITY, l_s = 0.f;       // per-lane: row q = q0 + lane16

        __syncthreads();
        for (int ii = 0; ii < 4; ii++) {
            const int f = w * 4 + ii;
            const int nt = f >> 2, kc = f & 3;
            ASYNC16(Kh + (size_t)(nt * 16 + lane16) * HD + kc * 32 + quad * 8, &kt[0][f * 512]);
            const int dt = f >> 1, kk = f & 1;
            ASYNC16(Vh + (size_t)(dt * 16 + lane16) * SEQ + kk * 32 + quad * 8, &vt[0][f * 512]);
        }

        int cur = 0;
        for (int kb = 0; kb <= qt; kb++) {
            const int k0 = kb * 64;
            __syncthreads();
            if (kb < qt) {
                const int kn = k0 + 64;
                for (int ii = 0; ii < 4; ii++) {
                    const int f = w * 4 + ii;
                    const int nt = f >> 2, kc = f & 3;
                    ASYNC16(Kh + (size_t)(kn + nt * 16 + lane16) * HD + kc * 32 + quad * 8,
                            &kt[1 - cur][f * 512]);
                    const int dt = f >> 1, kk = f & 1;
                    ASYNC16(Vh + (size_t)(dt * 16 + lane16) * SEQ + kn + kk * 32 + quad * 8,
                            &vt[1 - cur][f * 512]);
                }
            }
            const bf16_t* ktc = kt[cur];
            const bf16_t* vtc = vt[cur];

            f32x4 sacc[4];
            for (int nt = 0; nt < 4; nt++) sacc[nt] = (f32x4){0.f, 0.f, 0.f, 0.f};
            for (int nt = 0; nt < 4; nt++)
                for (int kc = 0; kc < 4; kc++) {
                    bf16x8 kf = *(const bf16x8*)&ktc[(nt * 4 + kc) * 512 + l * 8];
                    sacc[nt] = __builtin_amdgcn_mfma_f32_16x16x32_bf16(kf, qf[kc], sacc[nt], 0, 0, 0);
                }
            if (kb == qt) {
                const int qg = q0 + lane16;
                for (int nt = 0; nt < 4; nt++)
                    for (int r = 0; r < 4; r++) {
                        const int kg = k0 + nt * 16 + quad * 4 + r;
                        if (kg > qg) sacc[nt][r] = -INFINITY;
                    }
            }
            float rowmax = sacc[0][0];
            for (int nt = 0; nt < 4; nt++)
                for (int r = 0; r < 4; r++) rowmax = fmaxf(rowmax, sacc[nt][r]);
            rowmax = fmaxf(rowmax, __shfl_xor(rowmax, 16, 64));
            rowmax = fmaxf(rowmax, __shfl_xor(rowmax, 32, 64));
            const float mnew = fmaxf(m_s, rowmax);
            const float a = __expf(m_s - mnew);
            m_s = mnew;
            float ssum = 0.f;
            for (int nt = 0; nt < 4; nt++) {
                union { bf16_t h4[4]; uint2 u; } pk;
                for (int r = 0; r < 4; r++) {
                    const float e = __expf(sacc[nt][r] - mnew);
                    ssum += e;
                    pk.h4[r] = (bf16_t)e;
                }
                const int addr = (nt >> 1) * 512 +
                                 (((nt & 1) * 2 + (quad >> 1)) * 16 + lane16) * 8 +
                                 (quad & 1) * 4;
                *(uint2*)&pbuf[w][addr] = pk.u;
            }
            ssum += __shfl_xor(ssum, 16, 64);
            ssum += __shfl_xor(ssum, 32, 64);
            l_s = l_s * a + ssum;

            float ar[4];
            for (int r = 0; r < 4; r++) ar[r] = __shfl(a, (quad << 2) | r, 16);
            for (int dt = 0; dt < 8; dt++)
                for (int r = 0; r < 4; r++) o[dt][r] *= ar[r];
            for (int kk = 0; kk < 2; kk++) {
                bf16x8 pf = *(const bf16x8*)&pbuf[w][kk * 512 + l * 8];
                for (int dt = 0; dt < 8; dt++) {
                    bf16x8 vf = *(const bf16x8*)&vtc[(dt * 2 + kk) * 512 + l * 8];
                    o[dt] = __builtin_amdgcn_mfma_f32_16x16x32_bf16(pf, vf, o[dt], 0, 0, 0);
                }
            }
            cur ^= 1;
        }

        float inv[4];
        for (int r = 0; r < 4; r++) inv[r] = 1.0f / __shfl(l_s, (quad << 2) | r, 16);
        for (int r = 0; r < 4; r++) {
            const int qg = q0 + quad * 4 + r;
            bf16_t* dst = ctx + ((size_t)(b * SEQ + qg)) * (NH * HD) + h * HD;
            for (int dt = 0; dt < 8; dt++)
                dst[dt * 16 + lane16] = (bf16_t)(o[dt][r] * inv[r]);
        }
        __syncthreads();
    }
}

// ---------------------------------------------------------------- launch
extern "C" void kernel_launch(void* const* d_in, const int* in_sizes, int n_in,
                              void* d_out, int out_size, void* d_ws, size_t ws_size,
                              hipStream_t stream) {
    const float* x  = (const float*)d_in[0];
    const int* pos  = (const int*)d_in[1];
    const float* Wq = (const float*)d_in[2];
    const float* Wk = (const float*)d_in[3];
    const float* Wv = (const float*)d_in[4];
    const float* Wo = (const float*)d_in[5];

    char* ws = (char*)d_ws;
    bf16_t* xb   = (bf16_t*)(ws);
    bf16_t* wqkv = (bf16_t*)(ws + (16u << 20));   // [6144,2048]
    bf16_t* wob  = (bf16_t*)(ws + (40u << 20));
    bf16_t* Qb   = (bf16_t*)(ws + (48u << 20));
    bf16_t* Kb   = (bf16_t*)(ws + (64u << 20));
    bf16_t* Vt   = (bf16_t*)(ws + (80u << 20));
    bf16_t* ctx  = (bf16_t*)(ws + (96u << 20));

    cast_all<<<24576, 256, 0, stream>>>(x, Wq, Wk, Wv, Wo, xb, wqkv, wob);

    dim3 gq(6144 / 128, MM / 128);
    gemm_qkv<<<gq, 256, 0, stream>>>(xb, wqkv, Qb, Kb, Vt, pos);

    attn_kernel<<<512, 256, 0, stream>>>(Qb, Kb, Vt, ctx);

    dim3 gg(2048 / 128, MM / 128);
    gemm_out<<<gg, 256, 0, stream>>>(ctx, wob, (float*)d_out);
}